// Round 1
// baseline (4711.332 us; speedup 1.0000x reference)
//
#include <hip/hip_runtime.h>
#include <math.h>

typedef unsigned short u16;
typedef unsigned int   u32;
typedef __attribute__((ext_vector_type(4))) float f32x4;
typedef __attribute__((ext_vector_type(8))) short s16x8;

#define D_   1024
#define DE_  4096
#define H_   16
#define CHD_ 32
#define MHD_ 64
#define L_   6
#define B_   2
#define T_   1024
#define M_   (B_*T_)   // 2048
#define V_   32000
#define EPS_ 1e-5f

// ---- scalar helpers ----------------------------------------------------------
__device__ __forceinline__ float bf2f(u16 u){ return __uint_as_float(((u32)u) << 16); }
__device__ __forceinline__ u16 f2bf(float f){
    u32 x = __float_as_uint(f);
    return (u16)((x + 0x7fffu + ((x >> 16) & 1u)) >> 16);   // RNE
}
__device__ __forceinline__ float ldf(const void* p, size_t i, int f16){
    return f16 ? bf2f(((const u16*)p)[i]) : ((const float*)p)[i];
}
__device__ __forceinline__ float sigf(float x){ return 1.f / (1.f + __expf(-x)); }

// async global->LDS, 16B per lane; LDS dest must be wave-uniform base
typedef __attribute__((address_space(3))) u32 as3_u32;
typedef const __attribute__((address_space(1))) u32 as1_u32;
__device__ __forceinline__ void gld16(const void* g, void* l){
    __builtin_amdgcn_global_load_lds((as1_u32*)g, (as3_u32*)l, 16, 0, 0);
}
// slot swizzle: spreads ds_read_b128 rows across banks (2-way residual = free)
__device__ __forceinline__ int swz(int row){ return (row >> 1) & 3; }

// ---------------- dtype detection: bf16 weights have small exponents ----------
__global__ void detect_dtype(const u16* __restrict__ te_u16, int* __restrict__ flag){
    __shared__ int any_big;
    if (threadIdx.x == 0) any_big = 0;
    __syncthreads();
    int big = 0;
    #pragma unroll
    for (int i=0;i<4;i++){
        u16 u = te_u16[threadIdx.x + 256*i];
        int e = (u >> 7) & 0xFF;
        if (e >= 0x88) big = 1;          // |v| >= 512: impossible for real weights
    }
    if (big) any_big = 1;
    __syncthreads();
    if (threadIdx.x == 0) *flag = any_big ? 0 : 1;   // garbage found -> fp32
}

// ---------------- embedding: x[m,d] = te[ids[m],d] + pe[m%T,d] ----------------
__global__ __launch_bounds__(256) void embed_kernel(const int* __restrict__ ids,
        const void* __restrict__ te, const void* __restrict__ pe,
        float* __restrict__ x, const int* __restrict__ flagp){
    int f16 = *flagp;
    int idx = blockIdx.x*256 + threadIdx.x;
    int m = idx >> 10, d = idx & 1023;
    int t = m & (T_-1);
    x[idx] = ldf(te, (size_t)ids[m]*D_ + d, f16) + ldf(pe, (size_t)t*D_ + d, f16);
}

// ---------------- layernorm (row-per-block, 256 thr, D=1024) -> bf16 out ------
__device__ __forceinline__ float blk_sum(float v, float* smem){
    #pragma unroll
    for (int o=32;o>0;o>>=1) v += __shfl_xor(v, o);
    __syncthreads();
    if ((threadIdx.x & 63) == 0) smem[threadIdx.x>>6] = v;
    __syncthreads();
    return smem[0]+smem[1]+smem[2]+smem[3];
}

__global__ __launch_bounds__(256) void ln_kernel(const float* __restrict__ x,
        const void* __restrict__ g, const void* __restrict__ b, size_t goff,
        u16* __restrict__ out, const int* __restrict__ flagp){
    __shared__ float smem[4];
    int f16 = *flagp;
    int row = blockIdx.x, tid = threadIdx.x;
    const float* xr = x + (size_t)row*D_;
    float v[4]; float s = 0.f;
    #pragma unroll
    for (int i=0;i<4;i++){ v[i] = xr[tid+256*i]; s += v[i]; }
    float mean = blk_sum(s, smem) * (1.f/D_);
    float vs = 0.f;
    #pragma unroll
    for (int i=0;i<4;i++){ float d = v[i]-mean; vs += d*d; }
    float inv = rsqrtf(blk_sum(vs, smem)*(1.f/D_) + EPS_);
    u16* orow = out + (size_t)row*D_;
    #pragma unroll
    for (int i=0;i<4;i++){
        int c = tid+256*i;
        orow[c] = f2bf((v[i]-mean)*inv*ldf(g, goff+c, f16) + ldf(b, goff+c, f16));
    }
}

// ---------------- weight transpose + bf16 cast: Wt[n][k] = W[k][n] ------------
__global__ __launch_bounds__(256) void wt_tr(
        const void* s0, size_t o0, u16* d0,
        const void* s1, size_t o1, u16* d1,
        const void* s2, size_t o2, u16* d2,
        int K, int N, const int* __restrict__ flagp){
    const void* s; size_t o; u16* d;
    if (blockIdx.z == 0){ s=s0; o=o0; d=d0; }
    else if (blockIdx.z == 1){ s=s1; o=o1; d=d1; }
    else { s=s2; o=o2; d=d2; }
    int f16 = *flagp;
    __shared__ float tile[32][33];
    int k0 = blockIdx.y*32, n0 = blockIdx.x*32;
    int c = threadIdx.x & 31, r8 = threadIdx.x >> 5;
    #pragma unroll
    for (int i=0;i<4;i++){
        int r = r8 + i*8;
        tile[r][c] = ldf(s, o + (size_t)(k0+r)*N + n0 + c, f16);
    }
    __syncthreads();
    #pragma unroll
    for (int i=0;i<4;i++){
        int r = r8 + i*8;
        d[(size_t)(n0+r)*K + k0 + c] = f2bf(tile[c][r]);
    }
}

// ---------------- concat biases: b1[2048]=q|k|v, b2[5120]=exp|gate (fp32) -----
__global__ __launch_bounds__(256) void bias_cat(
        const void* qb_, const void* kb_, const void* vb_,
        const void* eb_, const void* gb_,
        size_t oq, size_t ok, size_t ov, size_t oe, size_t og,
        float* __restrict__ b1, float* __restrict__ b2,
        const int* __restrict__ flagp){
    int f16 = *flagp;
    int i = blockIdx.x*256 + threadIdx.x;   // 0..7167
    if (i < 2048){
        float v = (i < 512)  ? ldf(qb_, oq + i, f16)
                : (i < 1024) ? ldf(kb_, ok + i - 512, f16)
                :              ldf(vb_, ov + i - 1024, f16);
        b1[i] = v;
    } else {
        int j = i - 2048;
        float v = (j < DE_) ? ldf(eb_, oe + j, f16)
                            : ldf(gb_, og + j - DE_, f16);
        b2[j] = v;
    }
}

// ---------------- MFMA GEMM: C[M,N] = A[M,K] @ Bt[N,K]^T + bias ---------------
// m97 structure: 128x128 tile, BK=32, 4 waves (2x2), each wave 64x64 via 4x4
// mfma_f32_16x16x32_bf16 fragments. global_load_lds w16 staging with
// pre-swizzled source (slot ^= (row>>1)&3) -> 2-way LDS conflicts (free).
// MODE: 0 plain->bf16 (RESID: +=fp32)  2 gated in-place bf16
//       3 head (flagged out, no bias; fp32-B reg-stage-converted)
//       4 exp|gate split: silu for nc>=DE_
template<int MODE, bool RESID, bool BIASF32>
__global__ __launch_bounds__(256) void gemm_mfma(
        const u16* __restrict__ A, int lda,
        const void* __restrict__ B, int ldb,          // Bt[N][K], ldb = K
        const void* __restrict__ bias, size_t boff,
        void* __restrict__ C, int ldc,
        int N, int K, const int* __restrict__ flagp){
    __shared__ __align__(16) char smem[16384];
    char* ldsA = smem;
    char* ldsB = smem + 8192;
    const int t = threadIdx.x;
    const int w = t >> 6, lane = t & 63;
    const int fr = lane & 15, g = lane >> 4;
    const int wm = (w >> 1) * 64, wn = (w & 1) * 64;
    const int m0 = blockIdx.y * 128, n0 = blockIdx.x * 128;

    const int f16 = *flagp;
    const bool convB = (MODE == 3) && !f16;   // head with fp32 te: convert-stage

    // staging coords (gload path): thread t covers LDS bytes t*16 of each 4KB half
    const int srow = t >> 2, sslot = t & 3;
    const int aslot = sslot ^ swz(srow);
    const u16* srcA   = A + (size_t)(m0 + srow) * lda + 8 * aslot;
    const u16* srcB16 = (const u16*)B + (size_t)(n0 + srow) * ldb + 8 * aslot;
    // convert-stage coords: thread t covers LDS row t>>1, slots {2(t&1), 2(t&1)+1}
    const int crow = t >> 1;
    const int cs0 = (t & 1) * 2;
    const float* srcBf = (const float*)B + (size_t)(n0 + crow) * ldb;

    char* dstA = ldsA + w * 1024;
    char* dstB = ldsB + w * 1024;

    f32x4 acc[4][4];
    const f32x4 zero = {0.f, 0.f, 0.f, 0.f};
    #pragma unroll
    for (int i=0;i<4;i++)
        #pragma unroll
        for (int j=0;j<4;j++) acc[i][j] = zero;

    const int slotb = (g ^ swz(fr)) * 16;

    for (int k0 = 0; k0 < K; k0 += 32){
        gld16(srcA + k0,                      dstA);
        gld16(srcA + k0 + (size_t)64 * lda,   dstA + 4096);
        if (!convB){
            gld16(srcB16 + k0,                    dstB);
            gld16(srcB16 + k0 + (size_t)64 * ldb, dstB + 4096);
        } else {
            #pragma unroll
            for (int si=0; si<2; si++){
                int s = cs0 + si;
                const float* sp = srcBf + k0 + 8 * (s ^ swz(crow));
                float4 f0 = *(const float4*)sp;
                float4 f1 = *(const float4*)(sp + 4);
                s16x8 pk;
                pk[0]=(short)f2bf(f0.x); pk[1]=(short)f2bf(f0.y);
                pk[2]=(short)f2bf(f0.z); pk[3]=(short)f2bf(f0.w);
                pk[4]=(short)f2bf(f1.x); pk[5]=(short)f2bf(f1.y);
                pk[6]=(short)f2bf(f1.z); pk[7]=(short)f2bf(f1.w);
                *(s16x8*)(ldsB + crow*64 + s*16) = pk;
            }
        }
        __syncthreads();
        s16x8 a[4], b[4];
        #pragma unroll
        for (int mt=0;mt<4;mt++)
            a[mt] = *(const s16x8*)(ldsA + (wm + mt*16 + fr)*64 + slotb);
        #pragma unroll
        for (int nt=0;nt<4;nt++)
            b[nt] = *(const s16x8*)(ldsB + (wn + nt*16 + fr)*64 + slotb);
        #pragma unroll
        for (int mt=0;mt<4;mt++)
            #pragma unroll
            for (int nt=0;nt<4;nt++)
                acc[mt][nt] = __builtin_amdgcn_mfma_f32_16x16x32_bf16(
                                  a[mt], b[nt], acc[mt][nt], 0, 0, 0);
        __syncthreads();
    }

    // epilogue: C[row = wm+mt*16+g*4+r][col = wn+nt*16+fr]
    #pragma unroll
    for (int nt=0;nt<4;nt++){
        const int nc = n0 + wn + nt*16 + fr;
        float bv = 0.f;
        if (MODE != 3)
            bv = BIASF32 ? ((const float*)bias)[boff + nc]
                         : ldf(bias, boff + nc, f16);
        #pragma unroll
        for (int mt=0;mt<4;mt++){
            #pragma unroll
            for (int r=0;r<4;r++){
                const int mr = m0 + wm + mt*16 + g*4 + r;
                const size_t idx = (size_t)mr * ldc + nc;
                float val = acc[mt][nt][r] + bv;
                if (MODE == 4){
                    if (nc >= DE_) val = val * sigf(val);       // silu (gate part)
                    ((u16*)C)[idx] = f2bf(val);
                } else if (MODE == 2){
                    float e = bf2f(((const u16*)C)[idx]);
                    float z = e * sigf(val);
                    ((u16*)C)[idx] = f2bf(z * sigf(z));          // silu(e*g)
                } else if (MODE == 3){
                    if (f16) ((u16*)C)[idx] = f2bf(val);
                    else     ((float*)C)[idx] = val;
                } else if (RESID){
                    ((float*)C)[idx] += val;
                } else {
                    ((u16*)C)[idx] = f2bf(val);
                }
            }
        }
    }
}

// ---------------- causal attention, online softmax, one wave per (b,h,q) ------
// q/k/v packed in one [M][2048] bf16 buffer: q@0, k@512, v@1024
__global__ __launch_bounds__(64) void attn_kernel(const u16* __restrict__ qkv,
                                                  u16* __restrict__ y){
    int qi = blockIdx.x, h = blockIdx.y, b = blockIdx.z;
    int tid = threadIdx.x;
    __shared__ float qs[CHD_];
    __shared__ float ps[64];
    const u16* qrow = qkv + (size_t)(b*T_+qi)*2048 + h*CHD_;
    if (tid < CHD_) qs[tid] = bf2f(qrow[tid]);
    __syncthreads();
    const float scale = 0.17677669529663687f;   // 1/sqrt(32)
    float acc = 0.f, mrun = -INFINITY, lrun = 0.f;
    for (int j0 = 0; j0 <= qi; j0 += 64){
        int j = j0 + tid;
        bool valid = (j <= qi);
        float s = -3.0e38f;
        if (valid){
            const u32* kr = (const u32*)(qkv + (size_t)(b*T_+j)*2048 + 512 + h*CHD_);
            float d = 0.f;
            #pragma unroll
            for (int c=0;c<16;c++){
                u32 u = kr[c];
                d += qs[2*c]   * bf2f((u16)(u & 0xffffu));
                d += qs[2*c+1] * bf2f((u16)(u >> 16));
            }
            s = d * scale;
        }
        float cm = s;
        #pragma unroll
        for (int o=32;o>0;o>>=1) cm = fmaxf(cm, __shfl_xor(cm, o));
        float mnew = fmaxf(mrun, cm);
        float p = valid ? __expf(s - mnew) : 0.f;
        float alpha = (mrun == -INFINITY) ? 0.f : __expf(mrun - mnew);
        float psum = p;
        #pragma unroll
        for (int o=32;o>0;o>>=1) psum += __shfl_xor(psum, o);
        lrun = lrun*alpha + psum;
        acc  = acc*alpha;
        mrun = mnew;
        __syncthreads();
        ps[tid] = p;
        __syncthreads();
        const u16* vb = qkv + (size_t)(b*T_+j0)*2048 + 1024 + h*MHD_ + tid;
        int jmax = (qi - j0 + 1) < 64 ? (qi - j0 + 1) : 64;
        for (int jj=0; jj<jmax; jj++)
            acc += ps[jj] * bf2f(vb[(size_t)jj*2048]);
    }
    y[(size_t)(b*T_+qi)*(H_*MHD_) + h*MHD_ + tid] = f2bf(acc / lrun);
}

// ------------------------------------------------------------------------------
extern "C" void kernel_launch(void* const* d_in, const int* in_sizes, int n_in,
                              void* d_out, int out_size, void* d_ws, size_t ws_size,
                              hipStream_t stream){
    const int*  ids   = (const int*) d_in[0];
    const void* te    = d_in[1];
    const void* pe    = d_in[2];
    const void* ln1_g = d_in[3];
    const void* ln1_b = d_in[4];
    const void* qp_w  = d_in[5];
    const void* qp_b  = d_in[6];
    const void* kp_w  = d_in[7];
    const void* kp_b  = d_in[8];
    const void* vp_w  = d_in[9];
    const void* vp_b  = d_in[10];
    const void* out_w = d_in[11];
    const void* out_b = d_in[12];
    const void* ln2_g = d_in[13];
    const void* ln2_b = d_in[14];
    const void* exp_w = d_in[15];
    const void* exp_b = d_in[16];
    const void* gate_w= d_in[17];
    const void* gate_b= d_in[18];
    const void* gup_w = d_in[19];
    const void* gup_b = d_in[20];
    const void* comp_w= d_in[21];
    const void* comp_b= d_in[22];
    const void* lnf_g = d_in[23];
    const void* lnf_b = d_in[24];

    // workspace map (peak 43 MB <= previous kernel's proven 53 MB)
    char* ws = (char*)d_ws;
    int*   flag  = (int*)ws;
    float* bcat1 = (float*)(ws + 4096);                  // 2048 f32
    float* bcat2 = (float*)(ws + 4096 + 8192);           // 5120 f32
    float* x     = (float*)(ws + (1u<<20));              // [2048][1024] f32, 8MB
    u16*   hb    = (u16*)  (ws + (9u<<20));              // [2048][1024] bf16, 4MB
    u16*   qkvb  = (u16*)  (ws + (13u<<20));             // [2048][2048] bf16, 8MB (attn phase)
    u16*   yb    = (u16*)  (ws + (21u<<20));             // [2048][1024] bf16, 4MB (attn phase)
    u16*   eg1   = (u16*)  (ws + (13u<<20));             // [2048][5120] bf16, 20MB (ffn phase)
    u16*   wb    = (u16*)  (ws + (33u<<20));             // 10MB transposed-weight scratch

    detect_dtype<<<1, 256, 0, stream>>>((const u16*)te, flag);
    embed_kernel<<<(M_*D_)/256, 256, 0, stream>>>(ids, te, pe, x, flag);

    for (int l=0; l<L_; l++){
        size_t lD = (size_t)l*D_;
        // --- attention-phase weight staging: wb = [qT|kT|vT][2048][1024], outT @ +2M
        wt_tr<<<dim3(16,32,2), 256, 0, stream>>>(
            qp_w, (size_t)l*D_*512, wb,
            kp_w, (size_t)l*D_*512, wb + (size_t)512*1024,
            nullptr, 0, nullptr, 1024, 512, flag);
        wt_tr<<<dim3(32,32,2), 256, 0, stream>>>(
            vp_w,  (size_t)l*D_*1024,  wb + (size_t)1024*1024,
            out_w, (size_t)l*1024*1024, wb + (size_t)2048*1024,
            nullptr, 0, nullptr, 1024, 1024, flag);
        bias_cat<<<28, 256, 0, stream>>>(qp_b, kp_b, vp_b, exp_b, gate_b,
            (size_t)l*512, (size_t)l*512, (size_t)l*1024,
            (size_t)l*DE_, (size_t)l*1024, bcat1, bcat2, flag);

        ln_kernel<<<M_, 256, 0, stream>>>(x, ln1_g, ln1_b, lD, hb, flag);
        gemm_mfma<0,false,true><<<dim3(16,16), 256, 0, stream>>>(
            hb, 1024, wb, 1024, bcat1, 0, qkvb, 2048, 2048, 1024, flag);
        attn_kernel<<<dim3(T_,H_,B_), 64, 0, stream>>>(qkvb, yb);
        gemm_mfma<0,true,false><<<dim3(8,16), 256, 0, stream>>>(
            yb, 1024, wb + (size_t)2048*1024, 1024,
            out_b, (size_t)l*1024, x, 1024, 1024, 1024, flag);

        // --- ffn-phase weight staging (JIT, reuses wb) ---
        wt_tr<<<dim3(128,32,1), 256, 0, stream>>>(
            exp_w, (size_t)l*D_*DE_, wb,
            nullptr,0,nullptr, nullptr,0,nullptr, 1024, 4096, flag);
        wt_tr<<<dim3(32,32,1), 256, 0, stream>>>(
            gate_w, (size_t)l*D_*1024, wb + (size_t)4096*1024,
            nullptr,0,nullptr, nullptr,0,nullptr, 1024, 1024, flag);
        ln_kernel<<<M_, 256, 0, stream>>>(x, ln2_g, ln2_b, lD, hb, flag);
        gemm_mfma<4,false,true><<<dim3(40,16), 256, 0, stream>>>(
            hb, 1024, wb, 1024, bcat2, 0, eg1, 5120, 5120, 1024, flag);
        wt_tr<<<dim3(128,32,1), 256, 0, stream>>>(
            gup_w, (size_t)l*1024*DE_, wb,
            nullptr,0,nullptr, nullptr,0,nullptr, 1024, 4096, flag);
        gemm_mfma<2,false,false><<<dim3(32,16), 256, 0, stream>>>(
            eg1 + 4096, 5120, wb, 1024,
            gup_b, (size_t)l*DE_, eg1, 5120, 4096, 1024, flag);
        wt_tr<<<dim3(32,128,1), 256, 0, stream>>>(
            comp_w, (size_t)l*DE_*1024, wb,
            nullptr,0,nullptr, nullptr,0,nullptr, 4096, 1024, flag);
        gemm_mfma<0,true,false><<<dim3(8,16), 256, 0, stream>>>(
            eg1, 5120, wb, 4096, comp_b, (size_t)l*1024, x, 1024, 1024, 4096, flag);
    }

    ln_kernel<<<M_, 256, 0, stream>>>(x, lnf_g, lnf_b, 0, hb, flag);
    gemm_mfma<3,false,false><<<dim3(V_/128, M_/128), 256, 0, stream>>>(
        hb, 1024, te, 1024, nullptr, 0, d_out, V_, V_, 1024, flag);
}

// Round 2
// 2868.515 us; speedup vs baseline: 1.6424x; 1.6424x over previous
//
#include <hip/hip_runtime.h>
#include <math.h>

typedef unsigned short u16;
typedef unsigned int   u32;
typedef __attribute__((ext_vector_type(4))) float f32x4;
typedef __attribute__((ext_vector_type(8))) short s16x8;

#define D_   1024
#define DE_  4096
#define H_   16
#define CHD_ 32
#define MHD_ 64
#define L_   6
#define B_   2
#define T_   1024
#define M_   (B_*T_)   // 2048
#define V_   32000
#define EPS_ 1e-5f

// ---- scalar helpers ----------------------------------------------------------
__device__ __forceinline__ float bf2f(u16 u){ return __uint_as_float(((u32)u) << 16); }
__device__ __forceinline__ u16 f2bf(float f){
    u32 x = __float_as_uint(f);
    return (u16)((x + 0x7fffu + ((x >> 16) & 1u)) >> 16);   // RNE
}
__device__ __forceinline__ float ldf(const void* p, size_t i, int f16){
    return f16 ? bf2f(((const u16*)p)[i]) : ((const float*)p)[i];
}
__device__ __forceinline__ float sigf(float x){ return 1.f / (1.f + __expf(-x)); }

// async global->LDS, 16B per lane; LDS dest must be wave-uniform base
typedef __attribute__((address_space(3))) u32 as3_u32;
typedef const __attribute__((address_space(1))) u32 as1_u32;
__device__ __forceinline__ void gld16(const void* g, void* l){
    __builtin_amdgcn_global_load_lds((as1_u32*)g, (as3_u32*)l, 16, 0, 0);
}
// slot swizzle for 64B rows (4 slots): 2-way residual = free
__device__ __forceinline__ int swz(int row){ return (row >> 1) & 3; }

// ---------------- dtype detection: bf16 weights have small exponents ----------
__global__ void detect_dtype(const u16* __restrict__ te_u16, int* __restrict__ flag){
    __shared__ int any_big;
    if (threadIdx.x == 0) any_big = 0;
    __syncthreads();
    int big = 0;
    #pragma unroll
    for (int i=0;i<4;i++){
        u16 u = te_u16[threadIdx.x + 256*i];
        int e = (u >> 7) & 0xFF;
        if (e >= 0x88) big = 1;          // |v| >= 512: impossible for real weights
    }
    if (big) any_big = 1;
    __syncthreads();
    if (threadIdx.x == 0) *flag = any_big ? 0 : 1;   // garbage found -> fp32
}

// ---------------- embedding ---------------------------------------------------
__global__ __launch_bounds__(256) void embed_kernel(const int* __restrict__ ids,
        const void* __restrict__ te, const void* __restrict__ pe,
        float* __restrict__ x, const int* __restrict__ flagp){
    int f16 = *flagp;
    int idx = blockIdx.x*256 + threadIdx.x;
    int m = idx >> 10, d = idx & 1023;
    int t = m & (T_-1);
    x[idx] = ldf(te, (size_t)ids[m]*D_ + d, f16) + ldf(pe, (size_t)t*D_ + d, f16);
}

// ---------------- layernorm (row-per-block, 256 thr, D=1024) -> bf16 out ------
__device__ __forceinline__ float blk_sum(float v, float* smem){
    #pragma unroll
    for (int o=32;o>0;o>>=1) v += __shfl_xor(v, o);
    __syncthreads();
    if ((threadIdx.x & 63) == 0) smem[threadIdx.x>>6] = v;
    __syncthreads();
    return smem[0]+smem[1]+smem[2]+smem[3];
}

__global__ __launch_bounds__(256) void ln_kernel(const float* __restrict__ x,
        const void* __restrict__ g, const void* __restrict__ b, size_t goff,
        u16* __restrict__ out, const int* __restrict__ flagp){
    __shared__ float smem[4];
    int f16 = *flagp;
    int row = blockIdx.x, tid = threadIdx.x;
    const float* xr = x + (size_t)row*D_;
    float v[4]; float s = 0.f;
    #pragma unroll
    for (int i=0;i<4;i++){ v[i] = xr[tid+256*i]; s += v[i]; }
    float mean = blk_sum(s, smem) * (1.f/D_);
    float vs = 0.f;
    #pragma unroll
    for (int i=0;i<4;i++){ float d = v[i]-mean; vs += d*d; }
    float inv = rsqrtf(blk_sum(vs, smem)*(1.f/D_) + EPS_);
    u16* orow = out + (size_t)row*D_;
    #pragma unroll
    for (int i=0;i<4;i++){
        int c = tid+256*i;
        orow[c] = f2bf((v[i]-mean)*inv*ldf(g, goff+c, f16) + ldf(b, goff+c, f16));
    }
}

// ---------------- weight transpose + bf16 cast: Wt[n][k] = W[k][n] ------------
__global__ __launch_bounds__(256) void wt_tr(
        const void* s0, size_t o0, u16* d0,
        const void* s1, size_t o1, u16* d1,
        const void* s2, size_t o2, u16* d2,
        int K, int N, const int* __restrict__ flagp){
    const void* s; size_t o; u16* d;
    if (blockIdx.z == 0){ s=s0; o=o0; d=d0; }
    else if (blockIdx.z == 1){ s=s1; o=o1; d=d1; }
    else { s=s2; o=o2; d=d2; }
    int f16 = *flagp;
    __shared__ float tile[32][33];
    int k0 = blockIdx.y*32, n0 = blockIdx.x*32;
    int c = threadIdx.x & 31, r8 = threadIdx.x >> 5;
    #pragma unroll
    for (int i=0;i<4;i++){
        int r = r8 + i*8;
        tile[r][c] = ldf(s, o + (size_t)(k0+r)*N + n0 + c, f16);
    }
    __syncthreads();
    #pragma unroll
    for (int i=0;i<4;i++){
        int r = r8 + i*8;
        d[(size_t)(n0+r)*K + k0 + c] = f2bf(tile[c][r]);
    }
}

// ---------------- V transpose: vt[(b*16+h)*64+d][t] = qkv[b*T+t][1024+h*64+d] -
__global__ __launch_bounds__(256) void v_transpose(const u16* __restrict__ qkv,
                                                   u16* __restrict__ vt){
    __shared__ u16 tile[32][34];
    int bh = blockIdx.z, b = bh >> 4, h = bh & 15;
    int t0 = blockIdx.x*32, d0 = blockIdx.y*32;
    int c = threadIdx.x & 31, r8 = threadIdx.x >> 5;
    #pragma unroll
    for (int i=0;i<4;i++){
        int r = r8 + i*8;
        tile[r][c] = qkv[(size_t)(b*T_ + t0 + r)*2048 + 1024 + h*64 + d0 + c];
    }
    __syncthreads();
    #pragma unroll
    for (int i=0;i<4;i++){
        int r = r8 + i*8;
        vt[(size_t)(bh*64 + d0 + r)*T_ + t0 + c] = tile[c][r];
    }
}

// ---------------- concat biases -----------------------------------------------
__global__ __launch_bounds__(256) void bias_cat(
        const void* qb_, const void* kb_, const void* vb_,
        const void* eb_, const void* gb_,
        size_t oq, size_t ok, size_t ov, size_t oe, size_t og,
        float* __restrict__ b1, float* __restrict__ b2,
        const int* __restrict__ flagp){
    int f16 = *flagp;
    int i = blockIdx.x*256 + threadIdx.x;   // 0..7167
    if (i < 2048){
        float v = (i < 512)  ? ldf(qb_, oq + i, f16)
                : (i < 1024) ? ldf(kb_, ok + i - 512, f16)
                :              ldf(vb_, ov + i - 1024, f16);
        b1[i] = v;
    } else {
        int j = i - 2048;
        float v = (j < DE_) ? ldf(eb_, oe + j, f16)
                            : ldf(gb_, og + j - DE_, f16);
        b2[j] = v;
    }
}

// ---------------- MFMA GEMM: C[M,N] = A[M,K] @ Bt[N,K]^T + bias ---------------
// 128x128 tile, BK=32, 4 waves. Grid remap: bijective XCD swizzle + M-fastest
// so same-N panel blocks are XCD-local (te/weight panel read once per L2).
template<int MODE, bool RESID, bool BIASF32>
__global__ __launch_bounds__(256) void gemm_mfma(
        const u16* __restrict__ A, int lda,
        const void* __restrict__ B, int ldb,          // Bt[N][K], ldb = K
        const void* __restrict__ bias, size_t boff,
        void* __restrict__ C, int ldc,
        int N, int K, const int* __restrict__ flagp){
    __shared__ __align__(16) char smem[16384];
    char* ldsA = smem;
    char* ldsB = smem + 8192;
    const int t = threadIdx.x;
    const int w = t >> 6, lane = t & 63;
    const int fr = lane & 15, g = lane >> 4;
    const int wm = (w >> 1) * 64, wn = (w & 1) * 64;

    // grid remap: nwg % 8 == 0 for all launches (bijective)
    const int gx = gridDim.x, gy = gridDim.y;
    const int nwg = gx * gy;
    const int lin = blockIdx.y * gx + blockIdx.x;
    const int neu = (lin & 7) * (nwg >> 3) + (lin >> 3);
    const int m0 = (neu % gy) * 128;
    const int n0 = (neu / gy) * 128;

    const int f16 = *flagp;
    const bool convB = (MODE == 3) && !f16;   // head with fp32 te: convert-stage

    const int srow = t >> 2, sslot = t & 3;
    const int aslot = sslot ^ swz(srow);
    const u16* srcA   = A + (size_t)(m0 + srow) * lda + 8 * aslot;
    const u16* srcB16 = (const u16*)B + (size_t)(n0 + srow) * ldb + 8 * aslot;
    const int crow = t >> 1;
    const int cs0 = (t & 1) * 2;
    const float* srcBf = (const float*)B + (size_t)(n0 + crow) * ldb;

    char* dstA = ldsA + w * 1024;
    char* dstB = ldsB + w * 1024;

    f32x4 acc[4][4];
    const f32x4 zero = {0.f, 0.f, 0.f, 0.f};
    #pragma unroll
    for (int i=0;i<4;i++)
        #pragma unroll
        for (int j=0;j<4;j++) acc[i][j] = zero;

    const int slotb = (g ^ swz(fr)) * 16;

    for (int k0 = 0; k0 < K; k0 += 32){
        gld16(srcA + k0,                      dstA);
        gld16(srcA + k0 + (size_t)64 * lda,   dstA + 4096);
        if (!convB){
            gld16(srcB16 + k0,                    dstB);
            gld16(srcB16 + k0 + (size_t)64 * ldb, dstB + 4096);
        } else {
            #pragma unroll
            for (int si=0; si<2; si++){
                int s = cs0 + si;
                const float* sp = srcBf + k0 + 8 * (s ^ swz(crow));
                float4 f0 = *(const float4*)sp;
                float4 f1 = *(const float4*)(sp + 4);
                s16x8 pk;
                pk[0]=(short)f2bf(f0.x); pk[1]=(short)f2bf(f0.y);
                pk[2]=(short)f2bf(f0.z); pk[3]=(short)f2bf(f0.w);
                pk[4]=(short)f2bf(f1.x); pk[5]=(short)f2bf(f1.y);
                pk[6]=(short)f2bf(f1.z); pk[7]=(short)f2bf(f1.w);
                *(s16x8*)(ldsB + crow*64 + s*16) = pk;
            }
        }
        __syncthreads();
        s16x8 a[4], b[4];
        #pragma unroll
        for (int mt=0;mt<4;mt++)
            a[mt] = *(const s16x8*)(ldsA + (wm + mt*16 + fr)*64 + slotb);
        #pragma unroll
        for (int nt=0;nt<4;nt++)
            b[nt] = *(const s16x8*)(ldsB + (wn + nt*16 + fr)*64 + slotb);
        #pragma unroll
        for (int mt=0;mt<4;mt++)
            #pragma unroll
            for (int nt=0;nt<4;nt++)
                acc[mt][nt] = __builtin_amdgcn_mfma_f32_16x16x32_bf16(
                                  a[mt], b[nt], acc[mt][nt], 0, 0, 0);
        __syncthreads();
    }

    #pragma unroll
    for (int nt=0;nt<4;nt++){
        const int nc = n0 + wn + nt*16 + fr;
        float bv = 0.f;
        if (MODE != 3)
            bv = BIASF32 ? ((const float*)bias)[boff + nc]
                         : ldf(bias, boff + nc, f16);
        #pragma unroll
        for (int mt=0;mt<4;mt++){
            #pragma unroll
            for (int r=0;r<4;r++){
                const int mr = m0 + wm + mt*16 + g*4 + r;
                const size_t idx = (size_t)mr * ldc + nc;
                float val = acc[mt][nt][r] + bv;
                if (MODE == 4){
                    if (nc >= DE_) val = val * sigf(val);       // silu (gate part)
                    ((u16*)C)[idx] = f2bf(val);
                } else if (MODE == 2){
                    float e = bf2f(((const u16*)C)[idx]);
                    float z = e * sigf(val);
                    ((u16*)C)[idx] = f2bf(z * sigf(z));          // silu(e*g)
                } else if (MODE == 3){
                    if (f16) ((u16*)C)[idx] = f2bf(val);
                    else     ((float*)C)[idx] = val;
                } else if (RESID){
                    ((float*)C)[idx] += val;
                } else {
                    ((u16*)C)[idx] = f2bf(val);
                }
            }
        }
    }
}

// ---------------- MFMA flash attention ----------------------------------------
// Workgroup = 4 waves, 64 q-rows (16/wave). K-tiles of 64 staged to LDS via
// gld16 (pre-swizzled source); Vt ([b][h][d][t], j-contiguous) staged likewise.
// S = mfma(Q,K) (both natural layouts); online softmax in-register (shfl row
// reduce over 16-lane groups); P -> padded LDS -> A-frag for PV mfma.
__global__ __launch_bounds__(256) void attn_mfma(const u16* __restrict__ qkv,
                                                 const u16* __restrict__ vt,
                                                 u16* __restrict__ y){
    __shared__ __align__(16) char smem[21504];
    char* ldsK = smem;            // [64 j][32 d] bf16, 64B rows, swz slots
    char* ldsV = smem + 4096;     // [64 d][64 j] bf16, 128B rows, swz8 slots
    char* ldsP = smem + 12288;    // 4 x [16 q][72 j] bf16 (144B rows)

    const int qt = gridDim.x - 1 - blockIdx.x;     // long blocks first
    const int h = blockIdx.y, b = blockIdx.z;
    const int t = threadIdx.x, w = t >> 6, lane = t & 63;
    const int fr = lane & 15, g = lane >> 4;
    const int q0 = qt * 64;
    const int qw = q0 + w * 16;                    // wave's first q row
    const int bh = b * H_ + h;

    // staging coords
    const int srow = t >> 2, sslot = t & 3;        // K: 64 rows x 4 slots
    const u16* srcK = qkv + (size_t)(b*T_ + srow)*2048 + 512 + h*32
                      + 8 * (sslot ^ swz(srow));
    const int vrow = t >> 3, vslot = t & 7;        // Vt: 2 halves of 32 rows x 8 slots
    const u16* srcV0 = vt + (size_t)(bh*64 + vrow)*T_      + 8 * (vslot ^ (vrow & 7));
    const u16* srcV1 = vt + (size_t)(bh*64 + 32 + vrow)*T_ + 8 * (vslot ^ (vrow & 7));

    // Q fragment (A-operand, natural layout)
    s16x8 qf = *(const s16x8*)(qkv + (size_t)(b*T_ + qw + fr)*2048 + h*32 + g*8);

    char* pbase = ldsP + w * 2304;

    f32x4 o[4]; float m[4], l[4];
    #pragma unroll
    for (int f=0; f<4; f++) o[f] = (f32x4){0.f,0.f,0.f,0.f};
    #pragma unroll
    for (int r=0; r<4; r++){ m[r] = -3.0e38f; l[r] = 0.f; }

    const float scale = 0.17677669529663687f;      // 1/sqrt(32)
    const f32x4 zero = {0.f,0.f,0.f,0.f};

    for (int j0 = 0; j0 < q0 + 64; j0 += 64){
        __syncthreads();
        gld16(srcK + (size_t)j0*2048, ldsK + w*1024);
        gld16(srcV0 + j0,             ldsV + w*1024);
        gld16(srcV1 + j0,             ldsV + 4096 + w*1024);
        __syncthreads();
        if (j0 <= qw + 15){                        // wave-uniform
            // S = Q @ K^T
            f32x4 s[4];
            #pragma unroll
            for (int f=0; f<4; f++){
                int row = f*16 + fr;
                s16x8 kf = *(const s16x8*)(ldsK + row*64 + (g ^ swz(row))*16);
                s[f] = __builtin_amdgcn_mfma_f32_16x16x32_bf16(qf, kf, zero, 0,0,0);
            }
            // scale + causal mask
            bool needmask = (j0 + 63 > qw);
            #pragma unroll
            for (int f=0; f<4; f++){
                int j = j0 + f*16 + fr;
                #pragma unroll
                for (int r=0; r<4; r++){
                    float sv = s[f][r] * scale;
                    if (needmask && j > qw + g*4 + r) sv = -3.0e38f;
                    s[f][r] = sv;
                }
            }
            // row max (across f, then across 16-lane group)
            float mx[4];
            #pragma unroll
            for (int r=0; r<4; r++)
                mx[r] = fmaxf(fmaxf(s[0][r], s[1][r]), fmaxf(s[2][r], s[3][r]));
            #pragma unroll
            for (int o2=8; o2>0; o2>>=1)
                #pragma unroll
                for (int r=0; r<4; r++) mx[r] = fmaxf(mx[r], __shfl_xor(mx[r], o2));
            float al[4];
            #pragma unroll
            for (int r=0; r<4; r++){
                float mn = fmaxf(m[r], mx[r]);
                al[r] = __expf(m[r] - mn);
                m[r] = mn;
            }
            // P = exp(S - m), write to LDS, row sum
            float ps[4] = {0.f,0.f,0.f,0.f};
            #pragma unroll
            for (int f=0; f<4; f++)
                #pragma unroll
                for (int r=0; r<4; r++){
                    float p = __expf(s[f][r] - m[r]);
                    ps[r] += p;
                    *(u16*)(pbase + (g*4+r)*144 + (fr + 16*f)*2) = f2bf(p);
                }
            #pragma unroll
            for (int o2=8; o2>0; o2>>=1)
                #pragma unroll
                for (int r=0; r<4; r++) ps[r] += __shfl_xor(ps[r], o2);
            #pragma unroll
            for (int r=0; r<4; r++) l[r] = l[r]*al[r] + ps[r];
            // rescale O, then O += P @ V
            #pragma unroll
            for (int f=0; f<4; f++)
                #pragma unroll
                for (int r=0; r<4; r++) o[f][r] *= al[r];
            #pragma unroll
            for (int kk=0; kk<2; kk++){
                s16x8 pa = *(const s16x8*)(pbase + fr*144 + kk*64 + g*16);
                #pragma unroll
                for (int f=0; f<4; f++){
                    int row = f*16 + fr;
                    s16x8 vb = *(const s16x8*)(ldsV + row*128 + (((kk*4+g) ^ (row&7))*16));
                    o[f] = __builtin_amdgcn_mfma_f32_16x16x32_bf16(pa, vb, o[f], 0,0,0);
                }
            }
        }
    }
    // epilogue: y[b, q, h*64 + d] = O / l
    #pragma unroll
    for (int r=0; r<4; r++){
        float inv = 1.f / l[r];
        u16* yr = y + (size_t)(b*T_ + qw + g*4 + r)*1024 + h*64;
        #pragma unroll
        for (int f=0; f<4; f++)
            yr[fr + 16*f] = f2bf(o[f][r] * inv);
    }
}

// ------------------------------------------------------------------------------
extern "C" void kernel_launch(void* const* d_in, const int* in_sizes, int n_in,
                              void* d_out, int out_size, void* d_ws, size_t ws_size,
                              hipStream_t stream){
    const int*  ids   = (const int*) d_in[0];
    const void* te    = d_in[1];
    const void* pe    = d_in[2];
    const void* ln1_g = d_in[3];
    const void* ln1_b = d_in[4];
    const void* qp_w  = d_in[5];
    const void* qp_b  = d_in[6];
    const void* kp_w  = d_in[7];
    const void* kp_b  = d_in[8];
    const void* vp_w  = d_in[9];
    const void* vp_b  = d_in[10];
    const void* out_w = d_in[11];
    const void* out_b = d_in[12];
    const void* ln2_g = d_in[13];
    const void* ln2_b = d_in[14];
    const void* exp_w = d_in[15];
    const void* exp_b = d_in[16];
    const void* gate_w= d_in[17];
    const void* gate_b= d_in[18];
    const void* gup_w = d_in[19];
    const void* gup_b = d_in[20];
    const void* comp_w= d_in[21];
    const void* comp_b= d_in[22];
    const void* lnf_g = d_in[23];
    const void* lnf_b = d_in[24];

    char* ws = (char*)d_ws;
    int*   flag  = (int*)ws;
    float* bcat1 = (float*)(ws + 4096);                  // 2048 f32
    float* bcat2 = (float*)(ws + 4096 + 8192);           // 5120 f32
    float* x     = (float*)(ws + (1u<<20));              // [2048][1024] f32, 8MB
    u16*   hb    = (u16*)  (ws + (9u<<20));              // [2048][1024] bf16, 4MB
    u16*   qkvb  = (u16*)  (ws + (13u<<20));             // [2048][2048] bf16, 8MB (attn)
    u16*   yb    = (u16*)  (ws + (21u<<20));             // [2048][1024] bf16, 4MB (attn)
    u16*   vtb   = (u16*)  (ws + (25u<<20));             // [32][64][1024] bf16, 4MB (attn)
    u16*   eg1   = (u16*)  (ws + (13u<<20));             // [2048][5120] bf16, 20MB (ffn)
    u16*   wb    = (u16*)  (ws + (33u<<20));             // 10MB transposed-weight scratch

    detect_dtype<<<1, 256, 0, stream>>>((const u16*)te, flag);
    embed_kernel<<<(M_*D_)/256, 256, 0, stream>>>(ids, te, pe, x, flag);

    for (int l=0; l<L_; l++){
        size_t lD = (size_t)l*D_;
        wt_tr<<<dim3(16,32,2), 256, 0, stream>>>(
            qp_w, (size_t)l*D_*512, wb,
            kp_w, (size_t)l*D_*512, wb + (size_t)512*1024,
            nullptr, 0, nullptr, 1024, 512, flag);
        wt_tr<<<dim3(32,32,2), 256, 0, stream>>>(
            vp_w,  (size_t)l*D_*1024,  wb + (size_t)1024*1024,
            out_w, (size_t)l*1024*1024, wb + (size_t)2048*1024,
            nullptr, 0, nullptr, 1024, 1024, flag);
        bias_cat<<<28, 256, 0, stream>>>(qp_b, kp_b, vp_b, exp_b, gate_b,
            (size_t)l*512, (size_t)l*512, (size_t)l*1024,
            (size_t)l*DE_, (size_t)l*1024, bcat1, bcat2, flag);

        ln_kernel<<<M_, 256, 0, stream>>>(x, ln1_g, ln1_b, lD, hb, flag);
        gemm_mfma<0,false,true><<<dim3(16,16), 256, 0, stream>>>(
            hb, 1024, wb, 1024, bcat1, 0, qkvb, 2048, 2048, 1024, flag);
        v_transpose<<<dim3(32,2,32), 256, 0, stream>>>(qkvb, vtb);
        attn_mfma<<<dim3(T_/64, H_, B_), 256, 0, stream>>>(qkvb, vtb, yb);
        gemm_mfma<0,true,false><<<dim3(8,16), 256, 0, stream>>>(
            yb, 1024, wb + (size_t)2048*1024, 1024,
            out_b, (size_t)l*1024, x, 1024, 1024, 1024, flag);

        wt_tr<<<dim3(128,32,1), 256, 0, stream>>>(
            exp_w, (size_t)l*D_*DE_, wb,
            nullptr,0,nullptr, nullptr,0,nullptr, 1024, 4096, flag);
        wt_tr<<<dim3(32,32,1), 256, 0, stream>>>(
            gate_w, (size_t)l*D_*1024, wb + (size_t)4096*1024,
            nullptr,0,nullptr, nullptr,0,nullptr, 1024, 1024, flag);
        ln_kernel<<<M_, 256, 0, stream>>>(x, ln2_g, ln2_b, lD, hb, flag);
        gemm_mfma<4,false,true><<<dim3(40,16), 256, 0, stream>>>(
            hb, 1024, wb, 1024, bcat2, 0, eg1, 5120, 5120, 1024, flag);
        wt_tr<<<dim3(128,32,1), 256, 0, stream>>>(
            gup_w, (size_t)l*1024*DE_, wb,
            nullptr,0,nullptr, nullptr,0,nullptr, 1024, 4096, flag);
        gemm_mfma<2,false,false><<<dim3(32,16), 256, 0, stream>>>(
            eg1 + 4096, 5120, wb, 1024,
            gup_b, (size_t)l*DE_, eg1, 5120, 4096, 1024, flag);
        wt_tr<<<dim3(32,128,1), 256, 0, stream>>>(
            comp_w, (size_t)l*DE_*1024, wb,
            nullptr,0,nullptr, nullptr,0,nullptr, 4096, 1024, flag);
        gemm_mfma<0,true,false><<<dim3(8,16), 256, 0, stream>>>(
            eg1, 5120, wb, 4096, comp_b, (size_t)l*1024, x, 1024, 1024, 4096, flag);
    }

    ln_kernel<<<M_, 256, 0, stream>>>(x, lnf_g, lnf_b, 0, hb, flag);
    gemm_mfma<3,false,false><<<dim3(V_/128, M_/128), 256, 0, stream>>>(
        hb, 1024, te, 1024, nullptr, 0, d_out, V_, V_, 1024, flag);
}

// Round 3
// 2398.410 us; speedup vs baseline: 1.9644x; 1.1960x over previous
//
#include <hip/hip_runtime.h>
#include <math.h>

typedef unsigned short u16;
typedef unsigned int   u32;
typedef __attribute__((ext_vector_type(4))) float f32x4;
typedef __attribute__((ext_vector_type(8))) short s16x8;

#define D_   1024
#define DE_  4096
#define H_   16
#define CHD_ 32
#define MHD_ 64
#define L_   6
#define B_   2
#define T_   1024
#define M_   (B_*T_)   // 2048
#define V_   32000
#define EPS_ 1e-5f

// ---- scalar helpers ----------------------------------------------------------
__device__ __forceinline__ float bf2f(u16 u){ return __uint_as_float(((u32)u) << 16); }
__device__ __forceinline__ u16 f2bf(float f){
    u32 x = __float_as_uint(f);
    return (u16)((x + 0x7fffu + ((x >> 16) & 1u)) >> 16);   // RNE
}
__device__ __forceinline__ float ldf(const void* p, size_t i, int f16){
    return f16 ? bf2f(((const u16*)p)[i]) : ((const float*)p)[i];
}
__device__ __forceinline__ float sigf(float x){ return 1.f / (1.f + __expf(-x)); }

// async global->LDS, 16B per lane; LDS dest must be wave-uniform base
typedef __attribute__((address_space(3))) u32 as3_u32;
typedef const __attribute__((address_space(1))) u32 as1_u32;
__device__ __forceinline__ void gld16(const void* g, void* l){
    __builtin_amdgcn_global_load_lds((as1_u32*)g, (as3_u32*)l, 16, 0, 0);
}
// slot swizzle for 64B rows (4 slots): 2-way residual = free
__device__ __forceinline__ int swz(int row){ return (row >> 1) & 3; }

// ---------------- dtype detection: bf16 weights have small exponents ----------
__global__ void detect_dtype(const u16* __restrict__ te_u16, int* __restrict__ flag){
    __shared__ int any_big;
    if (threadIdx.x == 0) any_big = 0;
    __syncthreads();
    int big = 0;
    #pragma unroll
    for (int i=0;i<4;i++){
        u16 u = te_u16[threadIdx.x + 256*i];
        int e = (u >> 7) & 0xFF;
        if (e >= 0x88) big = 1;          // |v| >= 512: impossible for real weights
    }
    if (big) any_big = 1;
    __syncthreads();
    if (threadIdx.x == 0) *flag = any_big ? 0 : 1;   // garbage found -> fp32
}

// ---------------- te -> bf16 pre-convert (or copy when already bf16) ----------
__global__ __launch_bounds__(256) void conv_te(const void* __restrict__ te,
        u16* __restrict__ dst, const int* __restrict__ flagp){
    int f16 = *flagp;
    size_t i = ((size_t)blockIdx.x*256 + threadIdx.x)*8;
    if (f16){
        *(s16x8*)(dst+i) = *(const s16x8*)((const u16*)te + i);
    } else {
        const float* s = (const float*)te + i;
        float4 f0 = *(const float4*)s, f1 = *(const float4*)(s+4);
        s16x8 pk;
        pk[0]=(short)f2bf(f0.x); pk[1]=(short)f2bf(f0.y);
        pk[2]=(short)f2bf(f0.z); pk[3]=(short)f2bf(f0.w);
        pk[4]=(short)f2bf(f1.x); pk[5]=(short)f2bf(f1.y);
        pk[6]=(short)f2bf(f1.z); pk[7]=(short)f2bf(f1.w);
        *(s16x8*)(dst+i) = pk;
    }
}

// ---------------- embedding ---------------------------------------------------
__global__ __launch_bounds__(256) void embed_kernel(const int* __restrict__ ids,
        const void* __restrict__ te, const void* __restrict__ pe,
        float* __restrict__ x, const int* __restrict__ flagp){
    int f16 = *flagp;
    int idx = blockIdx.x*256 + threadIdx.x;
    int m = idx >> 10, d = idx & 1023;
    int t = m & (T_-1);
    x[idx] = ldf(te, (size_t)ids[m]*D_ + d, f16) + ldf(pe, (size_t)t*D_ + d, f16);
}

// ---------------- layernorm (row-per-block, 256 thr, D=1024) -> bf16 out ------
__device__ __forceinline__ float blk_sum(float v, float* smem){
    #pragma unroll
    for (int o=32;o>0;o>>=1) v += __shfl_xor(v, o);
    __syncthreads();
    if ((threadIdx.x & 63) == 0) smem[threadIdx.x>>6] = v;
    __syncthreads();
    return smem[0]+smem[1]+smem[2]+smem[3];
}

__global__ __launch_bounds__(256) void ln_kernel(const float* __restrict__ x,
        const void* __restrict__ g, const void* __restrict__ b, size_t goff,
        u16* __restrict__ out, const int* __restrict__ flagp){
    __shared__ float smem[4];
    int f16 = *flagp;
    int row = blockIdx.x, tid = threadIdx.x;
    const float* xr = x + (size_t)row*D_;
    float v[4]; float s = 0.f;
    #pragma unroll
    for (int i=0;i<4;i++){ v[i] = xr[tid+256*i]; s += v[i]; }
    float mean = blk_sum(s, smem) * (1.f/D_);
    float vs = 0.f;
    #pragma unroll
    for (int i=0;i<4;i++){ float d = v[i]-mean; vs += d*d; }
    float inv = rsqrtf(blk_sum(vs, smem)*(1.f/D_) + EPS_);
    u16* orow = out + (size_t)row*D_;
    #pragma unroll
    for (int i=0;i<4;i++){
        int c = tid+256*i;
        orow[c] = f2bf((v[i]-mean)*inv*ldf(g, goff+c, f16) + ldf(b, goff+c, f16));
    }
}

// ---------------- weight transpose + bf16 cast: Wt[n][k] = W[k][n] ------------
__global__ __launch_bounds__(256) void wt_tr(
        const void* s0, size_t o0, u16* d0,
        const void* s1, size_t o1, u16* d1,
        const void* s2, size_t o2, u16* d2,
        int K, int N, const int* __restrict__ flagp){
    const void* s; size_t o; u16* d;
    if (blockIdx.z == 0){ s=s0; o=o0; d=d0; }
    else if (blockIdx.z == 1){ s=s1; o=o1; d=d1; }
    else { s=s2; o=o2; d=d2; }
    int f16 = *flagp;
    __shared__ float tile[32][33];
    int k0 = blockIdx.y*32, n0 = blockIdx.x*32;
    int c = threadIdx.x & 31, r8 = threadIdx.x >> 5;
    #pragma unroll
    for (int i=0;i<4;i++){
        int r = r8 + i*8;
        tile[r][c] = ldf(s, o + (size_t)(k0+r)*N + n0 + c, f16);
    }
    __syncthreads();
    #pragma unroll
    for (int i=0;i<4;i++){
        int r = r8 + i*8;
        d[(size_t)(n0+r)*K + k0 + c] = f2bf(tile[c][r]);
    }
}

// ---------------- V transpose: vt[(b*16+h)*64+d][t] = qkv[b*T+t][1024+h*64+d] -
__global__ __launch_bounds__(256) void v_transpose(const u16* __restrict__ qkv,
                                                   u16* __restrict__ vt){
    __shared__ u16 tile[32][34];
    int bh = blockIdx.z, b = bh >> 4, h = bh & 15;
    int t0 = blockIdx.x*32, d0 = blockIdx.y*32;
    int c = threadIdx.x & 31, r8 = threadIdx.x >> 5;
    #pragma unroll
    for (int i=0;i<4;i++){
        int r = r8 + i*8;
        tile[r][c] = qkv[(size_t)(b*T_ + t0 + r)*2048 + 1024 + h*64 + d0 + c];
    }
    __syncthreads();
    #pragma unroll
    for (int i=0;i<4;i++){
        int r = r8 + i*8;
        vt[(size_t)(bh*64 + d0 + r)*T_ + t0 + c] = tile[c][r];
    }
}

// ---------------- concat biases -----------------------------------------------
__global__ __launch_bounds__(256) void bias_cat(
        const void* qb_, const void* kb_, const void* vb_,
        const void* eb_, const void* gb_,
        size_t oq, size_t ok, size_t ov, size_t oe, size_t og,
        float* __restrict__ b1, float* __restrict__ b2,
        const int* __restrict__ flagp){
    int f16 = *flagp;
    int i = blockIdx.x*256 + threadIdx.x;   // 0..7167
    if (i < 2048){
        float v = (i < 512)  ? ldf(qb_, oq + i, f16)
                : (i < 1024) ? ldf(kb_, ok + i - 512, f16)
                :              ldf(vb_, ov + i - 1024, f16);
        b1[i] = v;
    } else {
        int j = i - 2048;
        float v = (j < DE_) ? ldf(eb_, oe + j, f16)
                            : ldf(gb_, og + j - DE_, f16);
        b2[j] = v;
    }
}

// ---------------- MFMA GEMM: C[M,N] = A[M,K] @ Bt[N,K]^T + bias ---------------
// 128xTN tile, BK=32, 4 waves. TN=128: waves 2x2 (64x64 each). TN=64: waves
// 4x1 (32x64 each) -> 2x block count for small-N GEMMs (occupancy).
// SK>1: split-K over blockIdx.z, fp32 atomic accumulate (RESID only).
// MODE: 0 plain->bf16 (RESID: +=fp32)  2 gated in-place bf16
//       3 head, raw te (flagged; fp32 -> convert-stage)   4 exp|gate silu split
//       5 head, pre-converted bf16 te (fast path)
template<int MODE, bool RESID, bool BIASF32, int TN, int SK>
__global__ __launch_bounds__(256) void gemm_mfma(
        const u16* __restrict__ A, int lda,
        const void* __restrict__ B, int ldb,          // Bt[N][K], ldb = K
        const void* __restrict__ bias, size_t boff,
        void* __restrict__ C, int ldc,
        int N, int K, const int* __restrict__ flagp){
    constexpr int MT = (TN == 128) ? 4 : 2;
    constexpr int NT = 4;
    __shared__ __align__(16) char smem[8192 + TN*64];
    char* ldsA = smem;
    char* ldsB = smem + 8192;
    const int t = threadIdx.x;
    const int w = t >> 6, lane = t & 63;
    const int fr = lane & 15, g = lane >> 4;
    const int wm = (TN == 128) ? (w >> 1) * 64 : w * 32;
    const int wn = (TN == 128) ? (w & 1) * 64 : 0;

    // grid remap: bijective XCD swizzle + M-fastest (nwg % 8 == 0 everywhere)
    const int gx = gridDim.x, gy = gridDim.y;
    const int nwg = gx * gy;
    const int lin = blockIdx.y * gx + blockIdx.x;
    const int neu = (lin & 7) * (nwg >> 3) + (lin >> 3);
    const int m0 = (neu % gy) * 128;
    const int n0 = (neu / gy) * TN;

    const int f16 = *flagp;
    const bool convB = (MODE == 3) && !f16;   // raw fp32 te: convert-stage

    const int srow = t >> 2, sslot = t & 3;
    const int aslot = sslot ^ swz(srow);
    const u16* srcA   = A + (size_t)(m0 + srow) * lda + 8 * aslot;
    const u16* srcB16 = (const u16*)B + (size_t)(n0 + srow) * ldb + 8 * aslot;
    const int crow = t >> 1;
    const int cs0 = (t & 1) * 2;
    const float* srcBf = (const float*)B + (size_t)(n0 + crow) * ldb;

    char* dstA = ldsA + w * 1024;
    char* dstB = ldsB + w * 1024;

    f32x4 acc[MT][NT];
    const f32x4 zero = {0.f, 0.f, 0.f, 0.f};
    #pragma unroll
    for (int i=0;i<MT;i++)
        #pragma unroll
        for (int j=0;j<NT;j++) acc[i][j] = zero;

    const int slotb = (g ^ swz(fr)) * 16;

    const int kps  = K / SK;
    const int kbeg = (SK > 1) ? blockIdx.z * kps : 0;
    const int kend = kbeg + kps;

    for (int k0 = kbeg; k0 < kend; k0 += 32){
        gld16(srcA + k0,                      dstA);
        gld16(srcA + k0 + (size_t)64 * lda,   dstA + 4096);
        if (!convB){
            gld16(srcB16 + k0, dstB);
            if (TN == 128)
                gld16(srcB16 + k0 + (size_t)64 * ldb, dstB + 4096);
        } else {
            #pragma unroll
            for (int si=0; si<2; si++){
                int s = cs0 + si;
                const float* sp = srcBf + k0 + 8 * (s ^ swz(crow));
                float4 f0 = *(const float4*)sp;
                float4 f1 = *(const float4*)(sp + 4);
                s16x8 pk;
                pk[0]=(short)f2bf(f0.x); pk[1]=(short)f2bf(f0.y);
                pk[2]=(short)f2bf(f0.z); pk[3]=(short)f2bf(f0.w);
                pk[4]=(short)f2bf(f1.x); pk[5]=(short)f2bf(f1.y);
                pk[6]=(short)f2bf(f1.z); pk[7]=(short)f2bf(f1.w);
                *(s16x8*)(ldsB + crow*64 + s*16) = pk;
            }
        }
        __syncthreads();
        s16x8 a[MT], b[NT];
        #pragma unroll
        for (int mt=0;mt<MT;mt++)
            a[mt] = *(const s16x8*)(ldsA + (wm + mt*16 + fr)*64 + slotb);
        #pragma unroll
        for (int nt=0;nt<NT;nt++)
            b[nt] = *(const s16x8*)(ldsB + (wn + nt*16 + fr)*64 + slotb);
        #pragma unroll
        for (int mt=0;mt<MT;mt++)
            #pragma unroll
            for (int nt=0;nt<NT;nt++)
                acc[mt][nt] = __builtin_amdgcn_mfma_f32_16x16x32_bf16(
                                  a[mt], b[nt], acc[mt][nt], 0, 0, 0);
        __syncthreads();
    }

    const bool addb = (SK == 1) || (blockIdx.z == 0);
    #pragma unroll
    for (int nt=0;nt<NT;nt++){
        const int nc = n0 + wn + nt*16 + fr;
        float bv = 0.f;
        if (MODE != 3 && MODE != 5 && addb)
            bv = BIASF32 ? ((const float*)bias)[boff + nc]
                         : ldf(bias, boff + nc, f16);
        #pragma unroll
        for (int mt=0;mt<MT;mt++){
            #pragma unroll
            for (int r=0;r<4;r++){
                const int mr = m0 + wm + mt*16 + g*4 + r;
                const size_t idx = (size_t)mr * ldc + nc;
                float val = acc[mt][nt][r] + bv;
                if (MODE == 4){
                    if (nc >= DE_) val = val * sigf(val);       // silu (gate part)
                    ((u16*)C)[idx] = f2bf(val);
                } else if (MODE == 2){
                    float e = bf2f(((const u16*)C)[idx]);
                    float z = e * sigf(val);
                    ((u16*)C)[idx] = f2bf(z * sigf(z));          // silu(e*g)
                } else if (MODE == 3 || MODE == 5){
                    if (f16) ((u16*)C)[idx] = f2bf(val);
                    else     ((float*)C)[idx] = val;
                } else if (RESID){
                    if (SK > 1) unsafeAtomicAdd(&((float*)C)[idx], val);
                    else        ((float*)C)[idx] += val;
                } else {
                    ((u16*)C)[idx] = f2bf(val);
                }
            }
        }
    }
}

// ---------------- MFMA flash attention ----------------------------------------
__global__ __launch_bounds__(256) void attn_mfma(const u16* __restrict__ qkv,
                                                 const u16* __restrict__ vt,
                                                 u16* __restrict__ y){
    __shared__ __align__(16) char smem[21504];
    char* ldsK = smem;            // [64 j][32 d] bf16, 64B rows, swz slots
    char* ldsV = smem + 4096;     // [64 d][64 j] bf16, 128B rows, swz8 slots
    char* ldsP = smem + 12288;    // 4 x [16 q][72 j] bf16 (144B rows)

    const int qt = gridDim.x - 1 - blockIdx.x;     // long blocks first
    const int h = blockIdx.y, b = blockIdx.z;
    const int t = threadIdx.x, w = t >> 6, lane = t & 63;
    const int fr = lane & 15, g = lane >> 4;
    const int q0 = qt * 64;
    const int qw = q0 + w * 16;                    // wave's first q row
    const int bh = b * H_ + h;

    const int srow = t >> 2, sslot = t & 3;        // K: 64 rows x 4 slots
    const u16* srcK = qkv + (size_t)(b*T_ + srow)*2048 + 512 + h*32
                      + 8 * (sslot ^ swz(srow));
    const int vrow = t >> 3, vslot = t & 7;        // Vt: 2 halves of 32 rows x 8 slots
    const u16* srcV0 = vt + (size_t)(bh*64 + vrow)*T_      + 8 * (vslot ^ (vrow & 7));
    const u16* srcV1 = vt + (size_t)(bh*64 + 32 + vrow)*T_ + 8 * (vslot ^ (vrow & 7));

    s16x8 qf = *(const s16x8*)(qkv + (size_t)(b*T_ + qw + fr)*2048 + h*32 + g*8);

    char* pbase = ldsP + w * 2304;

    f32x4 o[4]; float m[4], l[4];
    #pragma unroll
    for (int f=0; f<4; f++) o[f] = (f32x4){0.f,0.f,0.f,0.f};
    #pragma unroll
    for (int r=0; r<4; r++){ m[r] = -3.0e38f; l[r] = 0.f; }

    const float scale = 0.17677669529663687f;      // 1/sqrt(32)
    const f32x4 zero = {0.f,0.f,0.f,0.f};

    for (int j0 = 0; j0 < q0 + 64; j0 += 64){
        __syncthreads();
        gld16(srcK + (size_t)j0*2048, ldsK + w*1024);
        gld16(srcV0 + j0,             ldsV + w*1024);
        gld16(srcV1 + j0,             ldsV + 4096 + w*1024);
        __syncthreads();
        if (j0 <= qw + 15){                        // wave-uniform
            f32x4 s[4];
            #pragma unroll
            for (int f=0; f<4; f++){
                int row = f*16 + fr;
                s16x8 kf = *(const s16x8*)(ldsK + row*64 + (g ^ swz(row))*16);
                s[f] = __builtin_amdgcn_mfma_f32_16x16x32_bf16(qf, kf, zero, 0,0,0);
            }
            bool needmask = (j0 + 63 > qw);
            #pragma unroll
            for (int f=0; f<4; f++){
                int j = j0 + f*16 + fr;
                #pragma unroll
                for (int r=0; r<4; r++){
                    float sv = s[f][r] * scale;
                    if (needmask && j > qw + g*4 + r) sv = -3.0e38f;
                    s[f][r] = sv;
                }
            }
            float mx[4];
            #pragma unroll
            for (int r=0; r<4; r++)
                mx[r] = fmaxf(fmaxf(s[0][r], s[1][r]), fmaxf(s[2][r], s[3][r]));
            #pragma unroll
            for (int o2=8; o2>0; o2>>=1)
                #pragma unroll
                for (int r=0; r<4; r++) mx[r] = fmaxf(mx[r], __shfl_xor(mx[r], o2));
            float al[4];
            #pragma unroll
            for (int r=0; r<4; r++){
                float mn = fmaxf(m[r], mx[r]);
                al[r] = __expf(m[r] - mn);
                m[r] = mn;
            }
            float ps[4] = {0.f,0.f,0.f,0.f};
            #pragma unroll
            for (int f=0; f<4; f++)
                #pragma unroll
                for (int r=0; r<4; r++){
                    float p = __expf(s[f][r] - m[r]);
                    ps[r] += p;
                    *(u16*)(pbase + (g*4+r)*144 + (fr + 16*f)*2) = f2bf(p);
                }
            #pragma unroll
            for (int o2=8; o2>0; o2>>=1)
                #pragma unroll
                for (int r=0; r<4; r++) ps[r] += __shfl_xor(ps[r], o2);
            #pragma unroll
            for (int r=0; r<4; r++) l[r] = l[r]*al[r] + ps[r];
            #pragma unroll
            for (int f=0; f<4; f++)
                #pragma unroll
                for (int r=0; r<4; r++) o[f][r] *= al[r];
            #pragma unroll
            for (int kk=0; kk<2; kk++){
                s16x8 pa = *(const s16x8*)(pbase + fr*144 + kk*64 + g*16);
                #pragma unroll
                for (int f=0; f<4; f++){
                    int row = f*16 + fr;
                    s16x8 vb = *(const s16x8*)(ldsV + row*128 + (((kk*4+g) ^ (row&7))*16));
                    o[f] = __builtin_amdgcn_mfma_f32_16x16x32_bf16(pa, vb, o[f], 0,0,0);
                }
            }
        }
    }
    #pragma unroll
    for (int r=0; r<4; r++){
        float inv = 1.f / l[r];
        u16* yr = y + (size_t)(b*T_ + qw + g*4 + r)*1024 + h*64;
        #pragma unroll
        for (int f=0; f<4; f++)
            yr[fr + 16*f] = f2bf(o[f][r] * inv);
    }
}

// ------------------------------------------------------------------------------
extern "C" void kernel_launch(void* const* d_in, const int* in_sizes, int n_in,
                              void* d_out, int out_size, void* d_ws, size_t ws_size,
                              hipStream_t stream){
    const int*  ids   = (const int*) d_in[0];
    const void* te    = d_in[1];
    const void* pe    = d_in[2];
    const void* ln1_g = d_in[3];
    const void* ln1_b = d_in[4];
    const void* qp_w  = d_in[5];
    const void* qp_b  = d_in[6];
    const void* kp_w  = d_in[7];
    const void* kp_b  = d_in[8];
    const void* vp_w  = d_in[9];
    const void* vp_b  = d_in[10];
    const void* out_w = d_in[11];
    const void* out_b = d_in[12];
    const void* ln2_g = d_in[13];
    const void* ln2_b = d_in[14];
    const void* exp_w = d_in[15];
    const void* exp_b = d_in[16];
    const void* gate_w= d_in[17];
    const void* gate_b= d_in[18];
    const void* gup_w = d_in[19];
    const void* gup_b = d_in[20];
    const void* comp_w= d_in[21];
    const void* comp_b= d_in[22];
    const void* lnf_g = d_in[23];
    const void* lnf_b = d_in[24];

    char* ws = (char*)d_ws;
    int*   flag  = (int*)ws;
    float* bcat1 = (float*)(ws + 4096);                  // 2048 f32
    float* bcat2 = (float*)(ws + 4096 + 8192);           // 5120 f32
    float* x     = (float*)(ws + (1u<<20));              // [2048][1024] f32, 8MB
    u16*   hb    = (u16*)  (ws + (9u<<20));              // [2048][1024] bf16, 4MB
    u16*   qkvb  = (u16*)  (ws + (13u<<20));             // [2048][2048] bf16, 8MB (attn)
    u16*   yb    = (u16*)  (ws + (21u<<20));             // [2048][1024] bf16, 4MB (attn)
    u16*   vtb   = (u16*)  (ws + (25u<<20));             // [32][64][1024] bf16, 4MB (attn)
    u16*   eg1   = (u16*)  (ws + (13u<<20));             // [2048][5120] bf16, 20MB (ffn)
    u16*   wb    = (u16*)  (ws + (33u<<20));             // 10MB transposed-weight scratch
    u16*   te16  = (u16*)  (ws + ((size_t)44<<20));      // 65.6MB bf16 te (optional)

    const size_t need = ((size_t)44<<20) + (size_t)V_*D_*2 + (1u<<20);
    const bool pre = (ws_size >= need);

    detect_dtype<<<1, 256, 0, stream>>>((const u16*)te, flag);
    if (pre)
        conv_te<<<(V_*D_)/2048, 256, 0, stream>>>(te, te16, flag);
    embed_kernel<<<(M_*D_)/256, 256, 0, stream>>>(ids, te, pe, x, flag);

    for (int l=0; l<L_; l++){
        size_t lD = (size_t)l*D_;
        wt_tr<<<dim3(16,32,2), 256, 0, stream>>>(
            qp_w, (size_t)l*D_*512, wb,
            kp_w, (size_t)l*D_*512, wb + (size_t)512*1024,
            nullptr, 0, nullptr, 1024, 512, flag);
        wt_tr<<<dim3(32,32,2), 256, 0, stream>>>(
            vp_w,  (size_t)l*D_*1024,  wb + (size_t)1024*1024,
            out_w, (size_t)l*1024*1024, wb + (size_t)2048*1024,
            nullptr, 0, nullptr, 1024, 1024, flag);
        bias_cat<<<28, 256, 0, stream>>>(qp_b, kp_b, vp_b, exp_b, gate_b,
            (size_t)l*512, (size_t)l*512, (size_t)l*1024,
            (size_t)l*DE_, (size_t)l*1024, bcat1, bcat2, flag);

        ln_kernel<<<M_, 256, 0, stream>>>(x, ln1_g, ln1_b, lD, hb, flag);
        gemm_mfma<0,false,true,64,1><<<dim3(32,16), 256, 0, stream>>>(
            hb, 1024, wb, 1024, bcat1, 0, qkvb, 2048, 2048, 1024, flag);
        v_transpose<<<dim3(32,2,32), 256, 0, stream>>>(qkvb, vtb);
        attn_mfma<<<dim3(T_/64, H_, B_), 256, 0, stream>>>(qkvb, vtb, yb);
        gemm_mfma<0,true,false,64,2><<<dim3(16,16,2), 256, 0, stream>>>(
            yb, 1024, wb + (size_t)2048*1024, 1024,
            out_b, (size_t)l*1024, x, 1024, 1024, 1024, flag);

        wt_tr<<<dim3(128,32,1), 256, 0, stream>>>(
            exp_w, (size_t)l*D_*DE_, wb,
            nullptr,0,nullptr, nullptr,0,nullptr, 1024, 4096, flag);
        wt_tr<<<dim3(32,32,1), 256, 0, stream>>>(
            gate_w, (size_t)l*D_*1024, wb + (size_t)4096*1024,
            nullptr,0,nullptr, nullptr,0,nullptr, 1024, 1024, flag);
        ln_kernel<<<M_, 256, 0, stream>>>(x, ln2_g, ln2_b, lD, hb, flag);
        gemm_mfma<4,false,true,128,1><<<dim3(40,16), 256, 0, stream>>>(
            hb, 1024, wb, 1024, bcat2, 0, eg1, 5120, 5120, 1024, flag);
        wt_tr<<<dim3(128,32,1), 256, 0, stream>>>(
            gup_w, (size_t)l*1024*DE_, wb,
            nullptr,0,nullptr, nullptr,0,nullptr, 1024, 4096, flag);
        gemm_mfma<2,false,false,128,1><<<dim3(32,16), 256, 0, stream>>>(
            eg1 + 4096, 5120, wb, 1024,
            gup_b, (size_t)l*DE_, eg1, 5120, 4096, 1024, flag);
        wt_tr<<<dim3(32,128,1), 256, 0, stream>>>(
            comp_w, (size_t)l*DE_*1024, wb,
            nullptr,0,nullptr, nullptr,0,nullptr, 4096, 1024, flag);
        gemm_mfma<0,true,false,64,2><<<dim3(16,16,2), 256, 0, stream>>>(
            eg1, 5120, wb, 4096, comp_b, (size_t)l*1024, x, 1024, 1024, 4096, flag);
    }

    ln_kernel<<<M_, 256, 0, stream>>>(x, lnf_g, lnf_b, 0, hb, flag);
    if (pre)
        gemm_mfma<5,false,false,128,1><<<dim3(V_/128, M_/128), 256, 0, stream>>>(
            hb, 1024, te16, 1024, nullptr, 0, d_out, V_, V_, 1024, flag);
    else
        gemm_mfma<3,false,false,128,1><<<dim3(V_/128, M_/128), 256, 0, stream>>>(
            hb, 1024, te, 1024, nullptr, 0, d_out, V_, V_, 1024, flag);
}

// Round 4
// 2169.975 us; speedup vs baseline: 2.1711x; 1.1053x over previous
//
#include <hip/hip_runtime.h>
#include <math.h>

typedef unsigned short u16;
typedef unsigned int   u32;
typedef __attribute__((ext_vector_type(4))) float f32x4;
typedef __attribute__((ext_vector_type(8))) short s16x8;

#define D_   1024
#define DE_  4096
#define H_   16
#define CHD_ 32
#define MHD_ 64
#define L_   6
#define B_   2
#define T_   1024
#define M_   (B_*T_)   // 2048
#define V_   32000
#define EPS_ 1e-5f

// ---- scalar helpers ----------------------------------------------------------
__device__ __forceinline__ float bf2f(u16 u){ return __uint_as_float(((u32)u) << 16); }
__device__ __forceinline__ u16 f2bf(float f){
    u32 x = __float_as_uint(f);
    return (u16)((x + 0x7fffu + ((x >> 16) & 1u)) >> 16);   // RNE
}
__device__ __forceinline__ float ldf(const void* p, size_t i, int f16){
    return f16 ? bf2f(((const u16*)p)[i]) : ((const float*)p)[i];
}
__device__ __forceinline__ float sigf(float x){ return 1.f / (1.f + __expf(-x)); }

// async global->LDS, 16B per lane; LDS dest must be wave-uniform base
typedef __attribute__((address_space(3))) u32 as3_u32;
typedef const __attribute__((address_space(1))) u32 as1_u32;
__device__ __forceinline__ void gld16(const void* g, void* l){
    __builtin_amdgcn_global_load_lds((as1_u32*)g, (as3_u32*)l, 16, 0, 0);
}
// slot swizzle for 64B rows (4 slots): 2-way residual = free
__device__ __forceinline__ int swz(int row){ return (row >> 1) & 3; }

// ---------------- dtype detection: bf16 weights have small exponents ----------
__global__ void detect_dtype(const u16* __restrict__ te_u16, int* __restrict__ flag){
    __shared__ int any_big;
    if (threadIdx.x == 0) any_big = 0;
    __syncthreads();
    int big = 0;
    #pragma unroll
    for (int i=0;i<4;i++){
        u16 u = te_u16[threadIdx.x + 256*i];
        int e = (u >> 7) & 0xFF;
        if (e >= 0x88) big = 1;          // |v| >= 512: impossible for real weights
    }
    if (big) any_big = 1;
    __syncthreads();
    if (threadIdx.x == 0) *flag = any_big ? 0 : 1;   // garbage found -> fp32
}

// ---------------- te -> bf16 pre-convert (or copy when already bf16) ----------
__global__ __launch_bounds__(256) void conv_te(const void* __restrict__ te,
        u16* __restrict__ dst, const int* __restrict__ flagp){
    int f16 = *flagp;
    size_t i = ((size_t)blockIdx.x*256 + threadIdx.x)*8;
    if (f16){
        *(s16x8*)(dst+i) = *(const s16x8*)((const u16*)te + i);
    } else {
        const float* s = (const float*)te + i;
        float4 f0 = *(const float4*)s, f1 = *(const float4*)(s+4);
        s16x8 pk;
        pk[0]=(short)f2bf(f0.x); pk[1]=(short)f2bf(f0.y);
        pk[2]=(short)f2bf(f0.z); pk[3]=(short)f2bf(f0.w);
        pk[4]=(short)f2bf(f1.x); pk[5]=(short)f2bf(f1.y);
        pk[6]=(short)f2bf(f1.z); pk[7]=(short)f2bf(f1.w);
        *(s16x8*)(dst+i) = pk;
    }
}

// ---------------- embedding ---------------------------------------------------
__global__ __launch_bounds__(256) void embed_kernel(const int* __restrict__ ids,
        const void* __restrict__ te, const void* __restrict__ pe,
        float* __restrict__ x, const int* __restrict__ flagp){
    int f16 = *flagp;
    int idx = blockIdx.x*256 + threadIdx.x;
    int m = idx >> 10, d = idx & 1023;
    int t = m & (T_-1);
    x[idx] = ldf(te, (size_t)ids[m]*D_ + d, f16) + ldf(pe, (size_t)t*D_ + d, f16);
}

// ---------------- layernorm (row-per-block, 256 thr, D=1024) -> bf16 out ------
__device__ __forceinline__ float blk_sum(float v, float* smem){
    #pragma unroll
    for (int o=32;o>0;o>>=1) v += __shfl_xor(v, o);
    __syncthreads();
    if ((threadIdx.x & 63) == 0) smem[threadIdx.x>>6] = v;
    __syncthreads();
    return smem[0]+smem[1]+smem[2]+smem[3];
}

__global__ __launch_bounds__(256) void ln_kernel(const float* __restrict__ x,
        const void* __restrict__ g, const void* __restrict__ b, size_t goff,
        u16* __restrict__ out, const int* __restrict__ flagp){
    __shared__ float smem[4];
    int f16 = *flagp;
    int row = blockIdx.x, tid = threadIdx.x;
    const float* xr = x + (size_t)row*D_;
    float v[4]; float s = 0.f;
    #pragma unroll
    for (int i=0;i<4;i++){ v[i] = xr[tid+256*i]; s += v[i]; }
    float mean = blk_sum(s, smem) * (1.f/D_);
    float vs = 0.f;
    #pragma unroll
    for (int i=0;i<4;i++){ float d = v[i]-mean; vs += d*d; }
    float inv = rsqrtf(blk_sum(vs, smem)*(1.f/D_) + EPS_);
    u16* orow = out + (size_t)row*D_;
    #pragma unroll
    for (int i=0;i<4;i++){
        int c = tid+256*i;
        orow[c] = f2bf((v[i]-mean)*inv*ldf(g, goff+c, f16) + ldf(b, goff+c, f16));
    }
}

// ---------------- weight transpose + bf16 cast: Wt[n][k] = W[k][n] ------------
// 64x64 tile, float4 loads, s16x8 stores.
__global__ __launch_bounds__(256) void wt_tr(
        const void* s0, size_t o0, u16* d0,
        const void* s1, size_t o1, u16* d1,
        const void* s2, size_t o2, u16* d2,
        int K, int N, const int* __restrict__ flagp){
    const void* s; size_t o; u16* d;
    if (blockIdx.z == 0){ s=s0; o=o0; d=d0; }
    else if (blockIdx.z == 1){ s=s1; o=o1; d=d1; }
    else { s=s2; o=o2; d=d2; }
    int f16 = *flagp;
    __shared__ float tile[64][65];
    int k0 = blockIdx.y*64, n0 = blockIdx.x*64;
    int t = threadIdx.x;
    if (!f16){
        int c4 = (t & 15)*4, r = t >> 4;
        const float* S = (const float*)s + o + (size_t)(k0 + r)*N + n0 + c4;
        #pragma unroll
        for (int i=0;i<4;i++){
            float4 v = *(const float4*)(S + (size_t)(16*i)*N);
            tile[r+16*i][c4+0] = v.x; tile[r+16*i][c4+1] = v.y;
            tile[r+16*i][c4+2] = v.z; tile[r+16*i][c4+3] = v.w;
        }
    } else {
        int c = t & 63, r4 = t >> 6;
        #pragma unroll
        for (int i=0;i<16;i++){
            int r = r4 + i*4;
            tile[r][c] = bf2f(((const u16*)s)[o + (size_t)(k0+r)*N + n0 + c]);
        }
    }
    __syncthreads();
    int n = t >> 2, kq = (t & 3)*16;
    s16x8 lo, hi;
    #pragma unroll
    for (int i=0;i<8;i++) lo[i] = (short)f2bf(tile[kq+i][n]);
    #pragma unroll
    for (int i=0;i<8;i++) hi[i] = (short)f2bf(tile[kq+8+i][n]);
    u16* D = d + (size_t)(n0+n)*K + k0 + kq;
    *(s16x8*)D = lo;
    *(s16x8*)(D+8) = hi;
}

// ---------------- V transpose: vt[(b*16+h)*64+d][t] = qkv[b*T+t][1024+h*64+d] -
__global__ __launch_bounds__(256) void v_transpose(const u16* __restrict__ qkv,
                                                   u16* __restrict__ vt){
    __shared__ u16 tile[32][34];
    int bh = blockIdx.z, b = bh >> 4, h = bh & 15;
    int t0 = blockIdx.x*32, d0 = blockIdx.y*32;
    int c = threadIdx.x & 31, r8 = threadIdx.x >> 5;
    #pragma unroll
    for (int i=0;i<4;i++){
        int r = r8 + i*8;
        tile[r][c] = qkv[(size_t)(b*T_ + t0 + r)*2048 + 1024 + h*64 + d0 + c];
    }
    __syncthreads();
    #pragma unroll
    for (int i=0;i<4;i++){
        int r = r8 + i*8;
        vt[(size_t)(bh*64 + d0 + r)*T_ + t0 + c] = tile[c][r];
    }
}

// ---------------- concat biases -----------------------------------------------
__global__ __launch_bounds__(256) void bias_cat(
        const void* qb_, const void* kb_, const void* vb_,
        const void* eb_, const void* gb_,
        size_t oq, size_t ok, size_t ov, size_t oe, size_t og,
        float* __restrict__ b1, float* __restrict__ b2,
        const int* __restrict__ flagp){
    int f16 = *flagp;
    int i = blockIdx.x*256 + threadIdx.x;   // 0..7167
    if (i < 2048){
        float v = (i < 512)  ? ldf(qb_, oq + i, f16)
                : (i < 1024) ? ldf(kb_, ok + i - 512, f16)
                :              ldf(vb_, ov + i - 1024, f16);
        b1[i] = v;
    } else {
        int j = i - 2048;
        float v = (j < DE_) ? ldf(eb_, oe + j, f16)
                            : ldf(gb_, og + j - DE_, f16);
        b2[j] = v;
    }
}

// ---------------- MFMA GEMM: C[M,N] = A[M,K] @ Bt[N,K]^T + bias ---------------
// 128xTN tile, BK=64 (half the barrier/drain events of BK=32), 4 waves.
// LDS rows are 128B (8 slots of 16B), slot XOR-swizzled by row&7 -> 2-way
// residual conflicts within 16-lane batches (free). Staged via gld16 with
// pre-swizzled global source.
// MODE: 0 plain->bf16 (RESID: +=fp32)  2 gated in-place bf16
//       3 head, raw te (flagged; fp32 -> convert-stage)   4 exp|gate silu split
//       5 head, pre-converted bf16 te (fast path)
template<int MODE, bool RESID, bool BIASF32, int TN, int SK>
__global__ __launch_bounds__(256) void gemm_mfma(
        const u16* __restrict__ A, int lda,
        const void* __restrict__ B, int ldb,          // Bt[N][K], ldb = K
        const void* __restrict__ bias, size_t boff,
        void* __restrict__ C, int ldc,
        int N, int K, const int* __restrict__ flagp){
    constexpr int MT = (TN == 128) ? 4 : 2;
    constexpr int NT = 4;
    constexpr int BCALLS = TN / 32;
    __shared__ __align__(16) char smem[16384 + TN*128];
    char* ldsA = smem;
    char* ldsB = smem + 16384;
    const int t = threadIdx.x;
    const int w = t >> 6, lane = t & 63;
    const int fr = lane & 15, g = lane >> 4;
    const int wm = (TN == 128) ? (w >> 1) * 64 : w * 32;
    const int wn = (TN == 128) ? (w & 1) * 64 : 0;

    // grid remap: bijective XCD swizzle + M-fastest (nwg % 8 == 0 everywhere)
    const int gx = gridDim.x, gy = gridDim.y;
    const int nwg = gx * gy;
    const int lin = blockIdx.y * gx + blockIdx.x;
    const int neu = (lin & 7) * (nwg >> 3) + (lin >> 3);
    const int m0 = (neu % gy) * 128;
    const int n0 = (neu / gy) * TN;

    const int f16 = *flagp;
    const bool convB = (MODE == 3) && !f16;   // raw fp32 te: convert-stage

    // staging: rows of 128B = 8 slots; thread t covers (row=t>>3, slot=t&7)
    const int srow = t >> 3, sslot = t & 7;
    const u16* srcA   = A + (size_t)(m0 + srow) * lda + 8 * (sslot ^ (srow & 7));
    const u16* srcB16 = (const u16*)B + (size_t)(n0 + srow) * ldb + 8 * (sslot ^ (srow & 7));
    // convB coords: thread t handles row t>>1, k-half t&1 (4 slots)
    const int crow = t >> 1, chalf = t & 1;
    const float* srcBf = (const float*)B + (size_t)(n0 + crow) * ldb;

    char* dstA = ldsA + w * 1024;
    char* dstB = ldsB + w * 1024;

    f32x4 acc[MT][NT];
    const f32x4 zero = {0.f, 0.f, 0.f, 0.f};
    #pragma unroll
    for (int i=0;i<MT;i++)
        #pragma unroll
        for (int j=0;j<NT;j++) acc[i][j] = zero;

    const int kps  = K / SK;
    const int kbeg = (SK > 1) ? blockIdx.z * kps : 0;
    const int kend = kbeg + kps;

    for (int k0 = kbeg; k0 < kend; k0 += 64){
        #pragma unroll
        for (int i=0;i<4;i++)
            gld16(srcA + (size_t)(32*i)*lda + k0, dstA + i*4096);
        if (!convB){
            #pragma unroll
            for (int i=0;i<BCALLS;i++)
                gld16(srcB16 + (size_t)(32*i)*ldb + k0, dstB + i*4096);
        } else {
            #pragma unroll
            for (int s4=0;s4<4;s4++){
                int sl = chalf*4 + s4;
                const float* sp = srcBf + k0 + 8*(sl ^ (crow & 7));
                float4 f0 = *(const float4*)sp;
                float4 f1 = *(const float4*)(sp + 4);
                s16x8 pk;
                pk[0]=(short)f2bf(f0.x); pk[1]=(short)f2bf(f0.y);
                pk[2]=(short)f2bf(f0.z); pk[3]=(short)f2bf(f0.w);
                pk[4]=(short)f2bf(f1.x); pk[5]=(short)f2bf(f1.y);
                pk[6]=(short)f2bf(f1.z); pk[7]=(short)f2bf(f1.w);
                *(s16x8*)(ldsB + crow*128 + sl*16) = pk;
            }
        }
        __syncthreads();
        #pragma unroll
        for (int kk=0;kk<2;kk++){
            const int so = ((kk*4 + g) ^ (fr & 7)) * 16;
            s16x8 a[MT], b[NT];
            #pragma unroll
            for (int mt=0;mt<MT;mt++)
                a[mt] = *(const s16x8*)(ldsA + (wm + mt*16 + fr)*128 + so);
            #pragma unroll
            for (int nt=0;nt<NT;nt++)
                b[nt] = *(const s16x8*)(ldsB + (wn + nt*16 + fr)*128 + so);
            #pragma unroll
            for (int mt=0;mt<MT;mt++)
                #pragma unroll
                for (int nt=0;nt<NT;nt++)
                    acc[mt][nt] = __builtin_amdgcn_mfma_f32_16x16x32_bf16(
                                      a[mt], b[nt], acc[mt][nt], 0, 0, 0);
        }
        __syncthreads();
    }

    const bool addb = (SK == 1) || (blockIdx.z == 0);
    #pragma unroll
    for (int nt=0;nt<NT;nt++){
        const int nc = n0 + wn + nt*16 + fr;
        float bv = 0.f;
        if (MODE != 3 && MODE != 5 && addb)
            bv = BIASF32 ? ((const float*)bias)[boff + nc]
                         : ldf(bias, boff + nc, f16);
        #pragma unroll
        for (int mt=0;mt<MT;mt++){
            #pragma unroll
            for (int r=0;r<4;r++){
                const int mr = m0 + wm + mt*16 + g*4 + r;
                const size_t idx = (size_t)mr * ldc + nc;
                float val = acc[mt][nt][r] + bv;
                if (MODE == 4){
                    if (nc >= DE_) val = val * sigf(val);       // silu (gate part)
                    ((u16*)C)[idx] = f2bf(val);
                } else if (MODE == 2){
                    float e = bf2f(((const u16*)C)[idx]);
                    float z = e * sigf(val);
                    ((u16*)C)[idx] = f2bf(z * sigf(z));          // silu(e*g)
                } else if (MODE == 3 || MODE == 5){
                    if (f16) ((u16*)C)[idx] = f2bf(val);
                    else     ((float*)C)[idx] = val;
                } else if (RESID){
                    if (SK > 1) unsafeAtomicAdd(&((float*)C)[idx], val);
                    else        ((float*)C)[idx] += val;
                } else {
                    ((u16*)C)[idx] = f2bf(val);
                }
            }
        }
    }
}

// ---------------- MFMA flash attention ----------------------------------------
__global__ __launch_bounds__(256) void attn_mfma(const u16* __restrict__ qkv,
                                                 const u16* __restrict__ vt,
                                                 u16* __restrict__ y){
    __shared__ __align__(16) char smem[21504];
    char* ldsK = smem;            // [64 j][32 d] bf16, 64B rows, swz slots
    char* ldsV = smem + 4096;     // [64 d][64 j] bf16, 128B rows, swz8 slots
    char* ldsP = smem + 12288;    // 4 x [16 q][72 j] bf16 (144B rows)

    const int qt = gridDim.x - 1 - blockIdx.x;     // long blocks first
    const int h = blockIdx.y, b = blockIdx.z;
    const int t = threadIdx.x, w = t >> 6, lane = t & 63;
    const int fr = lane & 15, g = lane >> 4;
    const int q0 = qt * 64;
    const int qw = q0 + w * 16;                    // wave's first q row
    const int bh = b * H_ + h;

    const int srow = t >> 2, sslot = t & 3;        // K: 64 rows x 4 slots
    const u16* srcK = qkv + (size_t)(b*T_ + srow)*2048 + 512 + h*32
                      + 8 * (sslot ^ swz(srow));
    const int vrow = t >> 3, vslot = t & 7;        // Vt: 2 halves of 32 rows x 8 slots
    const u16* srcV0 = vt + (size_t)(bh*64 + vrow)*T_      + 8 * (vslot ^ (vrow & 7));
    const u16* srcV1 = vt + (size_t)(bh*64 + 32 + vrow)*T_ + 8 * (vslot ^ (vrow & 7));

    s16x8 qf = *(const s16x8*)(qkv + (size_t)(b*T_ + qw + fr)*2048 + h*32 + g*8);

    char* pbase = ldsP + w * 2304;

    f32x4 o[4]; float m[4], l[4];
    #pragma unroll
    for (int f=0; f<4; f++) o[f] = (f32x4){0.f,0.f,0.f,0.f};
    #pragma unroll
    for (int r=0; r<4; r++){ m[r] = -3.0e38f; l[r] = 0.f; }

    const float scale = 0.17677669529663687f;      // 1/sqrt(32)
    const f32x4 zero = {0.f,0.f,0.f,0.f};

    for (int j0 = 0; j0 < q0 + 64; j0 += 64){
        __syncthreads();
        gld16(srcK + (size_t)j0*2048, ldsK + w*1024);
        gld16(srcV0 + j0,             ldsV + w*1024);
        gld16(srcV1 + j0,             ldsV + 4096 + w*1024);
        __syncthreads();
        if (j0 <= qw + 15){                        // wave-uniform
            f32x4 s[4];
            #pragma unroll
            for (int f=0; f<4; f++){
                int row = f*16 + fr;
                s16x8 kf = *(const s16x8*)(ldsK + row*64 + (g ^ swz(row))*16);
                s[f] = __builtin_amdgcn_mfma_f32_16x16x32_bf16(qf, kf, zero, 0,0,0);
            }
            bool needmask = (j0 + 63 > qw);
            #pragma unroll
            for (int f=0; f<4; f++){
                int j = j0 + f*16 + fr;
                #pragma unroll
                for (int r=0; r<4; r++){
                    float sv = s[f][r] * scale;
                    if (needmask && j > qw + g*4 + r) sv = -3.0e38f;
                    s[f][r] = sv;
                }
            }
            float mx[4];
            #pragma unroll
            for (int r=0; r<4; r++)
                mx[r] = fmaxf(fmaxf(s[0][r], s[1][r]), fmaxf(s[2][r], s[3][r]));
            #pragma unroll
            for (int o2=8; o2>0; o2>>=1)
                #pragma unroll
                for (int r=0; r<4; r++) mx[r] = fmaxf(mx[r], __shfl_xor(mx[r], o2));
            float al[4];
            #pragma unroll
            for (int r=0; r<4; r++){
                float mn = fmaxf(m[r], mx[r]);
                al[r] = __expf(m[r] - mn);
                m[r] = mn;
            }
            float ps[4] = {0.f,0.f,0.f,0.f};
            #pragma unroll
            for (int f=0; f<4; f++)
                #pragma unroll
                for (int r=0; r<4; r++){
                    float p = __expf(s[f][r] - m[r]);
                    ps[r] += p;
                    *(u16*)(pbase + (g*4+r)*144 + (fr + 16*f)*2) = f2bf(p);
                }
            #pragma unroll
            for (int o2=8; o2>0; o2>>=1)
                #pragma unroll
                for (int r=0; r<4; r++) ps[r] += __shfl_xor(ps[r], o2);
            #pragma unroll
            for (int r=0; r<4; r++) l[r] = l[r]*al[r] + ps[r];
            #pragma unroll
            for (int f=0; f<4; f++)
                #pragma unroll
                for (int r=0; r<4; r++) o[f][r] *= al[r];
            #pragma unroll
            for (int kk=0; kk<2; kk++){
                s16x8 pa = *(const s16x8*)(pbase + fr*144 + kk*64 + g*16);
                #pragma unroll
                for (int f=0; f<4; f++){
                    int row = f*16 + fr;
                    s16x8 vb = *(const s16x8*)(ldsV + row*128 + (((kk*4+g) ^ (row&7))*16));
                    o[f] = __builtin_amdgcn_mfma_f32_16x16x32_bf16(pa, vb, o[f], 0,0,0);
                }
            }
        }
    }
    #pragma unroll
    for (int r=0; r<4; r++){
        float inv = 1.f / l[r];
        u16* yr = y + (size_t)(b*T_ + qw + g*4 + r)*1024 + h*64;
        #pragma unroll
        for (int f=0; f<4; f++)
            yr[fr + 16*f] = f2bf(o[f][r] * inv);
    }
}

// ------------------------------------------------------------------------------
extern "C" void kernel_launch(void* const* d_in, const int* in_sizes, int n_in,
                              void* d_out, int out_size, void* d_ws, size_t ws_size,
                              hipStream_t stream){
    const int*  ids   = (const int*) d_in[0];
    const void* te    = d_in[1];
    const void* pe    = d_in[2];
    const void* ln1_g = d_in[3];
    const void* ln1_b = d_in[4];
    const void* qp_w  = d_in[5];
    const void* qp_b  = d_in[6];
    const void* kp_w  = d_in[7];
    const void* kp_b  = d_in[8];
    const void* vp_w  = d_in[9];
    const void* vp_b  = d_in[10];
    const void* out_w = d_in[11];
    const void* out_b = d_in[12];
    const void* ln2_g = d_in[13];
    const void* ln2_b = d_in[14];
    const void* exp_w = d_in[15];
    const void* exp_b = d_in[16];
    const void* gate_w= d_in[17];
    const void* gate_b= d_in[18];
    const void* gup_w = d_in[19];
    const void* gup_b = d_in[20];
    const void* comp_w= d_in[21];
    const void* comp_b= d_in[22];
    const void* lnf_g = d_in[23];
    const void* lnf_b = d_in[24];

    char* ws = (char*)d_ws;
    int*   flag  = (int*)ws;
    float* bcat1 = (float*)(ws + 4096);                  // 2048 f32
    float* bcat2 = (float*)(ws + 4096 + 8192);           // 5120 f32
    float* x     = (float*)(ws + (1u<<20));              // [2048][1024] f32, 8MB
    u16*   hb    = (u16*)  (ws + (9u<<20));              // [2048][1024] bf16, 4MB
    u16*   qkvb  = (u16*)  (ws + (13u<<20));             // [2048][2048] bf16, 8MB (attn)
    u16*   yb    = (u16*)  (ws + (21u<<20));             // [2048][1024] bf16, 4MB (attn)
    u16*   vtb   = (u16*)  (ws + (25u<<20));             // [32][64][1024] bf16, 4MB (attn)
    u16*   eg1   = (u16*)  (ws + (13u<<20));             // [2048][5120] bf16, 20MB (ffn)
    u16*   wb    = (u16*)  (ws + (33u<<20));             // 10MB transposed-weight scratch
    u16*   te16  = (u16*)  (ws + ((size_t)44<<20));      // 65.6MB bf16 te (optional)

    const size_t need = ((size_t)44<<20) + (size_t)V_*D_*2 + (1u<<20);
    const bool pre = (ws_size >= need);

    detect_dtype<<<1, 256, 0, stream>>>((const u16*)te, flag);
    if (pre)
        conv_te<<<(V_*D_)/2048, 256, 0, stream>>>(te, te16, flag);
    embed_kernel<<<(M_*D_)/256, 256, 0, stream>>>(ids, te, pe, x, flag);

    for (int l=0; l<L_; l++){
        size_t lD = (size_t)l*D_;
        wt_tr<<<dim3(8,16,2), 256, 0, stream>>>(
            qp_w, (size_t)l*D_*512, wb,
            kp_w, (size_t)l*D_*512, wb + (size_t)512*1024,
            nullptr, 0, nullptr, 1024, 512, flag);
        wt_tr<<<dim3(16,16,2), 256, 0, stream>>>(
            vp_w,  (size_t)l*D_*1024,  wb + (size_t)1024*1024,
            out_w, (size_t)l*1024*1024, wb + (size_t)2048*1024,
            nullptr, 0, nullptr, 1024, 1024, flag);
        bias_cat<<<28, 256, 0, stream>>>(qp_b, kp_b, vp_b, exp_b, gate_b,
            (size_t)l*512, (size_t)l*512, (size_t)l*1024,
            (size_t)l*DE_, (size_t)l*1024, bcat1, bcat2, flag);

        ln_kernel<<<M_, 256, 0, stream>>>(x, ln1_g, ln1_b, lD, hb, flag);
        gemm_mfma<0,false,true,64,1><<<dim3(32,16), 256, 0, stream>>>(
            hb, 1024, wb, 1024, bcat1, 0, qkvb, 2048, 2048, 1024, flag);
        v_transpose<<<dim3(32,2,32), 256, 0, stream>>>(qkvb, vtb);
        attn_mfma<<<dim3(T_/64, H_, B_), 256, 0, stream>>>(qkvb, vtb, yb);
        gemm_mfma<0,true,false,64,2><<<dim3(16,16,2), 256, 0, stream>>>(
            yb, 1024, wb + (size_t)2048*1024, 1024,
            out_b, (size_t)l*1024, x, 1024, 1024, 1024, flag);

        wt_tr<<<dim3(64,16,1), 256, 0, stream>>>(
            exp_w, (size_t)l*D_*DE_, wb,
            nullptr,0,nullptr, nullptr,0,nullptr, 1024, 4096, flag);
        wt_tr<<<dim3(16,16,1), 256, 0, stream>>>(
            gate_w, (size_t)l*D_*1024, wb + (size_t)4096*1024,
            nullptr,0,nullptr, nullptr,0,nullptr, 1024, 1024, flag);
        ln_kernel<<<M_, 256, 0, stream>>>(x, ln2_g, ln2_b, lD, hb, flag);
        gemm_mfma<4,false,true,128,1><<<dim3(40,16), 256, 0, stream>>>(
            hb, 1024, wb, 1024, bcat2, 0, eg1, 5120, 5120, 1024, flag);
        wt_tr<<<dim3(64,16,1), 256, 0, stream>>>(
            gup_w, (size_t)l*1024*DE_, wb,
            nullptr,0,nullptr, nullptr,0,nullptr, 1024, 4096, flag);
        gemm_mfma<2,false,false,128,1><<<dim3(32,16), 256, 0, stream>>>(
            eg1 + 4096, 5120, wb, 1024,
            gup_b, (size_t)l*DE_, eg1, 5120, 4096, 1024, flag);
        wt_tr<<<dim3(16,64,1), 256, 0, stream>>>(
            comp_w, (size_t)l*DE_*1024, wb,
            nullptr,0,nullptr, nullptr,0,nullptr, 4096, 1024, flag);
        gemm_mfma<0,true,false,64,2><<<dim3(16,16,2), 256, 0, stream>>>(
            eg1, 5120, wb, 4096, comp_b, (size_t)l*1024, x, 1024, 1024, 4096, flag);
    }

    ln_kernel<<<M_, 256, 0, stream>>>(x, lnf_g, lnf_b, 0, hb, flag);
    if (pre)
        gemm_mfma<5,false,false,128,1><<<dim3(V_/128, M_/128), 256, 0, stream>>>(
            hb, 1024, te16, 1024, nullptr, 0, d_out, V_, V_, 1024, flag);
    else
        gemm_mfma<3,false,false,128,1><<<dim3(V_/128, M_/128), 256, 0, stream>>>(
            hb, 1024, te, 1024, nullptr, 0, d_out, V_, V_, 1024, flag);
}

// Round 5
// 2025.818 us; speedup vs baseline: 2.3256x; 1.0712x over previous
//
#include <hip/hip_runtime.h>
#include <math.h>

typedef unsigned short u16;
typedef unsigned int   u32;
typedef __attribute__((ext_vector_type(4))) float f32x4;
typedef __attribute__((ext_vector_type(8))) short s16x8;

#define D_   1024
#define DE_  4096
#define H_   16
#define CHD_ 32
#define MHD_ 64
#define L_   6
#define B_   2
#define T_   1024
#define M_   (B_*T_)   // 2048
#define V_   32000
#define EPS_ 1e-5f

// ---- scalar helpers ----------------------------------------------------------
__device__ __forceinline__ float bf2f(u16 u){ return __uint_as_float(((u32)u) << 16); }
__device__ __forceinline__ u16 f2bf(float f){
    u32 x = __float_as_uint(f);
    return (u16)((x + 0x7fffu + ((x >> 16) & 1u)) >> 16);   // RNE
}
__device__ __forceinline__ float ldf(const void* p, size_t i, int f16){
    return f16 ? bf2f(((const u16*)p)[i]) : ((const float*)p)[i];
}
__device__ __forceinline__ float sigf(float x){ return 1.f / (1.f + __expf(-x)); }

// async global->LDS, 16B per lane; LDS dest must be wave-uniform base
typedef __attribute__((address_space(3))) u32 as3_u32;
typedef const __attribute__((address_space(1))) u32 as1_u32;
typedef __attribute__((address_space(3))) const char as3c;
__device__ __forceinline__ void gld16(const void* g, void* l){
    __builtin_amdgcn_global_load_lds((as1_u32*)g, (as3_u32*)l, 16, 0, 0);
}
// inline-asm ds_read_b128: opaque to the memory legalizer, so our counted
// vmcnt waits stay counted (rule #18: pair with lgkmcnt(0)+sched_barrier(0))
__device__ __forceinline__ s16x8 dsr(const char* p){
    s16x8 v;
    u32 off = (u32)(size_t)(as3c*)p;
    asm volatile("ds_read_b128 %0, %1" : "=v"(v) : "v"(off));
    return v;
}
#define LGKM0()  asm volatile("s_waitcnt lgkmcnt(0)" ::: "memory")
#define SCHED0() __builtin_amdgcn_sched_barrier(0)
#define SBAR()   __builtin_amdgcn_s_barrier()
template<int N> __device__ __forceinline__ void vmwait(){
    asm volatile("s_waitcnt vmcnt(%0)" :: "n"(N) : "memory");
}
// slot swizzle for 64B rows (4 slots): 2-way residual = free
__device__ __forceinline__ int swz(int row){ return (row >> 1) & 3; }

// ---------------- dtype detection: bf16 weights have small exponents ----------
__global__ void detect_dtype(const u16* __restrict__ te_u16, int* __restrict__ flag){
    __shared__ int any_big;
    if (threadIdx.x == 0) any_big = 0;
    __syncthreads();
    int big = 0;
    #pragma unroll
    for (int i=0;i<4;i++){
        u16 u = te_u16[threadIdx.x + 256*i];
        int e = (u >> 7) & 0xFF;
        if (e >= 0x88) big = 1;          // |v| >= 512: impossible for real weights
    }
    if (big) any_big = 1;
    __syncthreads();
    if (threadIdx.x == 0) *flag = any_big ? 0 : 1;   // garbage found -> fp32
}

// ---------------- te -> bf16 pre-convert (or copy when already bf16) ----------
__global__ __launch_bounds__(256) void conv_te(const void* __restrict__ te,
        u16* __restrict__ dst, const int* __restrict__ flagp){
    int f16 = *flagp;
    size_t i = ((size_t)blockIdx.x*256 + threadIdx.x)*8;
    if (f16){
        *(s16x8*)(dst+i) = *(const s16x8*)((const u16*)te + i);
    } else {
        const float* s = (const float*)te + i;
        float4 f0 = *(const float4*)s, f1 = *(const float4*)(s+4);
        s16x8 pk;
        pk[0]=(short)f2bf(f0.x); pk[1]=(short)f2bf(f0.y);
        pk[2]=(short)f2bf(f0.z); pk[3]=(short)f2bf(f0.w);
        pk[4]=(short)f2bf(f1.x); pk[5]=(short)f2bf(f1.y);
        pk[6]=(short)f2bf(f1.z); pk[7]=(short)f2bf(f1.w);
        *(s16x8*)(dst+i) = pk;
    }
}

// ---------------- embedding ---------------------------------------------------
__global__ __launch_bounds__(256) void embed_kernel(const int* __restrict__ ids,
        const void* __restrict__ te, const void* __restrict__ pe,
        float* __restrict__ x, const int* __restrict__ flagp){
    int f16 = *flagp;
    int idx = blockIdx.x*256 + threadIdx.x;
    int m = idx >> 10, d = idx & 1023;
    int t = m & (T_-1);
    x[idx] = ldf(te, (size_t)ids[m]*D_ + d, f16) + ldf(pe, (size_t)t*D_ + d, f16);
}

// ---------------- layernorm (row-per-block, 256 thr, D=1024) -> bf16 out ------
__device__ __forceinline__ float blk_sum(float v, float* smem){
    #pragma unroll
    for (int o=32;o>0;o>>=1) v += __shfl_xor(v, o);
    __syncthreads();
    if ((threadIdx.x & 63) == 0) smem[threadIdx.x>>6] = v;
    __syncthreads();
    return smem[0]+smem[1]+smem[2]+smem[3];
}

__global__ __launch_bounds__(256) void ln_kernel(const float* __restrict__ x,
        const void* __restrict__ g, const void* __restrict__ b, size_t goff,
        u16* __restrict__ out, const int* __restrict__ flagp){
    __shared__ float smem[4];
    int f16 = *flagp;
    int row = blockIdx.x, tid = threadIdx.x;
    const float* xr = x + (size_t)row*D_;
    float v[4]; float s = 0.f;
    #pragma unroll
    for (int i=0;i<4;i++){ v[i] = xr[tid+256*i]; s += v[i]; }
    float mean = blk_sum(s, smem) * (1.f/D_);
    float vs = 0.f;
    #pragma unroll
    for (int i=0;i<4;i++){ float d = v[i]-mean; vs += d*d; }
    float inv = rsqrtf(blk_sum(vs, smem)*(1.f/D_) + EPS_);
    u16* orow = out + (size_t)row*D_;
    #pragma unroll
    for (int i=0;i<4;i++){
        int c = tid+256*i;
        orow[c] = f2bf((v[i]-mean)*inv*ldf(g, goff+c, f16) + ldf(b, goff+c, f16));
    }
}

// ---------------- weight transpose + bf16 cast: Wt[n][k] = W[k][n] ------------
__global__ __launch_bounds__(256) void wt_tr(
        const void* s0, size_t o0, u16* d0,
        const void* s1, size_t o1, u16* d1,
        const void* s2, size_t o2, u16* d2,
        int K, int N, const int* __restrict__ flagp){
    const void* s; size_t o; u16* d;
    if (blockIdx.z == 0){ s=s0; o=o0; d=d0; }
    else if (blockIdx.z == 1){ s=s1; o=o1; d=d1; }
    else { s=s2; o=o2; d=d2; }
    int f16 = *flagp;
    __shared__ float tile[64][65];
    int k0 = blockIdx.y*64, n0 = blockIdx.x*64;
    int t = threadIdx.x;
    if (!f16){
        int c4 = (t & 15)*4, r = t >> 4;
        const float* S = (const float*)s + o + (size_t)(k0 + r)*N + n0 + c4;
        #pragma unroll
        for (int i=0;i<4;i++){
            float4 v = *(const float4*)(S + (size_t)(16*i)*N);
            tile[r+16*i][c4+0] = v.x; tile[r+16*i][c4+1] = v.y;
            tile[r+16*i][c4+2] = v.z; tile[r+16*i][c4+3] = v.w;
        }
    } else {
        int c = t & 63, r4 = t >> 6;
        #pragma unroll
        for (int i=0;i<16;i++){
            int r = r4 + i*4;
            tile[r][c] = bf2f(((const u16*)s)[o + (size_t)(k0+r)*N + n0 + c]);
        }
    }
    __syncthreads();
    int n = t >> 2, kq = (t & 3)*16;
    s16x8 lo, hi;
    #pragma unroll
    for (int i=0;i<8;i++) lo[i] = (short)f2bf(tile[kq+i][n]);
    #pragma unroll
    for (int i=0;i<8;i++) hi[i] = (short)f2bf(tile[kq+8+i][n]);
    u16* D = d + (size_t)(n0+n)*K + k0 + kq;
    *(s16x8*)D = lo;
    *(s16x8*)(D+8) = hi;
}

// ---------------- V transpose: vt[(b*16+h)*64+d][t] = qkv[b*T+t][1024+h*64+d] -
__global__ __launch_bounds__(256) void v_transpose(const u16* __restrict__ qkv,
                                                   u16* __restrict__ vt){
    __shared__ u16 tile[32][34];
    int bh = blockIdx.z, b = bh >> 4, h = bh & 15;
    int t0 = blockIdx.x*32, d0 = blockIdx.y*32;
    int c = threadIdx.x & 31, r8 = threadIdx.x >> 5;
    #pragma unroll
    for (int i=0;i<4;i++){
        int r = r8 + i*8;
        tile[r][c] = qkv[(size_t)(b*T_ + t0 + r)*2048 + 1024 + h*64 + d0 + c];
    }
    __syncthreads();
    #pragma unroll
    for (int i=0;i<4;i++){
        int r = r8 + i*8;
        vt[(size_t)(bh*64 + d0 + r)*T_ + t0 + c] = tile[c][r];
    }
}

// ---------------- concat biases -----------------------------------------------
__global__ __launch_bounds__(256) void bias_cat(
        const void* qb_, const void* kb_, const void* vb_,
        const void* eb_, const void* gb_,
        size_t oq, size_t ok, size_t ov, size_t oe, size_t og,
        float* __restrict__ b1, float* __restrict__ b2,
        const int* __restrict__ flagp){
    int f16 = *flagp;
    int i = blockIdx.x*256 + threadIdx.x;   // 0..7167
    if (i < 2048){
        float v = (i < 512)  ? ldf(qb_, oq + i, f16)
                : (i < 1024) ? ldf(kb_, ok + i - 512, f16)
                :              ldf(vb_, ov + i - 1024, f16);
        b1[i] = v;
    } else {
        int j = i - 2048;
        float v = (j < DE_) ? ldf(eb_, oe + j, f16)
                            : ldf(gb_, og + j - DE_, f16);
        b2[j] = v;
    }
}

// ---------------- staging helper for pipelined GEMM ---------------------------
template<int BC>
__device__ __forceinline__ void stage_ab(const u16* sA, const u16* sB,
        int lda, int ldb, char* dA, char* dB, int k0){
    #pragma unroll
    for (int i=0;i<4;i++)  gld16(sA + (size_t)(32*i)*lda + k0, dA + i*4096);
    #pragma unroll
    for (int i=0;i<BC;i++) gld16(sB + (size_t)(32*i)*ldb + k0, dB + i*4096);
}

// ---------------- pipelined MFMA GEMM (T3+T4: dbuf + counted vmcnt) -----------
// C[M,N] = A[M,K] @ Bt[N,K]^T + bias.  128xTN tile, BK=64, 4 waves, double-
// buffered LDS, raw barriers, counted vmcnt (never drains in-flight prefetch).
// MODE: 0 plain->bf16 (RESID: +=fp32)  2 gated in-place bf16
//       4 exp|gate silu split           5 head (flagged out dtype, no bias)
template<int MODE, bool RESID, bool BIASF32, int TN, int SK>
__global__ __launch_bounds__(256) void gemm_pipe(
        const u16* __restrict__ A, int lda,
        const u16* __restrict__ B, int ldb,          // Bt[N][K] bf16, ldb = K
        const void* __restrict__ bias, size_t boff,
        void* __restrict__ C, int ldc,
        int N, int K, const int* __restrict__ flagp){
    constexpr int MT = (TN == 128) ? 4 : 2;
    constexpr int NT = 4;
    constexpr int BC = TN / 32;              // B-stage gld16 calls
    constexpr int L  = 4 + BC;               // loads per stage per thread
    constexpr int BUFSZ = 16384 + TN*128;
    __shared__ __align__(16) char smem[2*BUFSZ];
    const int t = threadIdx.x;
    const int w = t >> 6, lane = t & 63;
    const int fr = lane & 15, g = lane >> 4;
    const int wm = (TN == 128) ? (w >> 1) * 64 : w * 32;
    const int wn = (TN == 128) ? (w & 1) * 64 : 0;

    // bijective XCD swizzle + M-fastest (nwg % 8 == 0 everywhere)
    const int gx = gridDim.x, gy = gridDim.y;
    const int nwg = gx * gy;
    const int lin = blockIdx.y * gx + blockIdx.x;
    const int neu = (lin & 7) * (nwg >> 3) + (lin >> 3);
    const int m0 = (neu % gy) * 128;
    const int n0 = (neu / gy) * TN;

    const int f16 = *flagp;

    const int srow = t >> 3, sslot = t & 7;
    const u16* srcA = A + (size_t)(m0 + srow) * lda + 8 * (sslot ^ (srow & 7));
    const u16* srcB = B + (size_t)(n0 + srow) * ldb + 8 * (sslot ^ (srow & 7));

    f32x4 acc[MT][NT];
    #pragma unroll
    for (int i=0;i<MT;i++)
        #pragma unroll
        for (int j=0;j<NT;j++) acc[i][j] = (f32x4){0.f,0.f,0.f,0.f};

    const int kps  = K / SK;
    const int kbeg = (SK > 1) ? blockIdx.z * kps : 0;
    const int nt_  = kps >> 6;

    stage_ab<BC>(srcA, srcB, lda, ldb,
                 smem + w*1024, smem + 16384 + w*1024, kbeg);
    for (int it=0; it<nt_; ++it){
        const int cur = it & 1;
        if (it+1 < nt_){
            const int nb = cur^1;
            stage_ab<BC>(srcA, srcB, lda, ldb,
                         smem + nb*BUFSZ + w*1024,
                         smem + nb*BUFSZ + 16384 + w*1024,
                         kbeg + (it+1)*64);
            vmwait<L>();             // tile it landed; tile it+1 stays in flight
        } else {
            vmwait<0>();
        }
        SBAR();
        const char* bA = smem + cur*BUFSZ;
        const char* bB = smem + cur*BUFSZ + 16384;
        #pragma unroll
        for (int kk=0;kk<2;kk++){
            const int so = ((kk*4 + g) ^ (fr & 7)) * 16;
            s16x8 a[MT], b[NT];
            #pragma unroll
            for (int mt=0;mt<MT;mt++)
                a[mt] = dsr(bA + (wm + mt*16 + fr)*128 + so);
            #pragma unroll
            for (int n2=0;n2<NT;n2++)
                b[n2] = dsr(bB + (wn + n2*16 + fr)*128 + so);
            LGKM0(); SCHED0();
            #pragma unroll
            for (int mt=0;mt<MT;mt++)
                #pragma unroll
                for (int n2=0;n2<NT;n2++)
                    acc[mt][n2] = __builtin_amdgcn_mfma_f32_16x16x32_bf16(
                                      a[mt], b[n2], acc[mt][n2], 0, 0, 0);
        }
        SBAR();                      // WAR: next stage overwrites buf[cur]
    }

    const bool addb = (SK == 1) || (blockIdx.z == 0);
    #pragma unroll
    for (int n2=0;n2<NT;n2++){
        const int nc = n0 + wn + n2*16 + fr;
        float bv = 0.f;
        if (MODE != 5 && addb)
            bv = BIASF32 ? ((const float*)bias)[boff + nc]
                         : ldf(bias, boff + nc, f16);
        #pragma unroll
        for (int mt=0;mt<MT;mt++){
            #pragma unroll
            for (int r=0;r<4;r++){
                const int mr = m0 + wm + mt*16 + g*4 + r;
                const size_t idx = (size_t)mr * ldc + nc;
                float val = acc[mt][n2][r] + bv;
                if (MODE == 4){
                    if (nc >= DE_) val = val * sigf(val);       // silu (gate part)
                    ((u16*)C)[idx] = f2bf(val);
                } else if (MODE == 2){
                    float e = bf2f(((const u16*)C)[idx]);
                    float z = e * sigf(val);
                    ((u16*)C)[idx] = f2bf(z * sigf(z));          // silu(e*g)
                } else if (MODE == 5){
                    if (f16) ((u16*)C)[idx] = f2bf(val);
                    else     ((float*)C)[idx] = val;
                } else if (RESID){
                    if (SK > 1) unsafeAtomicAdd(&((float*)C)[idx], val);
                    else        ((float*)C)[idx] += val;
                } else {
                    ((u16*)C)[idx] = f2bf(val);
                }
            }
        }
    }
}

// ---------------- old-style GEMM kept only for fp32-te head fallback ----------
__global__ __launch_bounds__(256) void gemm_head_f32(
        const u16* __restrict__ A, int lda,
        const void* __restrict__ B, int ldb,
        void* __restrict__ C, int ldc,
        int N, int K, const int* __restrict__ flagp){
    __shared__ __align__(16) char smem[16384 + 16384];
    char* ldsA = smem;
    char* ldsB = smem + 16384;
    const int t = threadIdx.x;
    const int w = t >> 6, lane = t & 63;
    const int fr = lane & 15, g = lane >> 4;
    const int wm = (w >> 1) * 64, wn = (w & 1) * 64;
    const int gx = gridDim.x, gy = gridDim.y;
    const int nwg = gx * gy;
    const int lin = blockIdx.y * gx + blockIdx.x;
    const int neu = (lin & 7) * (nwg >> 3) + (lin >> 3);
    const int m0 = (neu % gy) * 128;
    const int n0 = (neu / gy) * 128;
    const int f16 = *flagp;
    const int srow = t >> 3, sslot = t & 7;
    const u16* srcA = A + (size_t)(m0 + srow) * lda + 8 * (sslot ^ (srow & 7));
    const u16* srcB16 = (const u16*)B + (size_t)(n0 + srow) * ldb + 8 * (sslot ^ (srow & 7));
    const int crow = t >> 1, chalf = t & 1;
    const float* srcBf = (const float*)B + (size_t)(n0 + crow) * ldb;
    f32x4 acc[4][4];
    #pragma unroll
    for (int i=0;i<4;i++)
        #pragma unroll
        for (int j=0;j<4;j++) acc[i][j] = (f32x4){0.f,0.f,0.f,0.f};
    for (int k0 = 0; k0 < K; k0 += 64){
        #pragma unroll
        for (int i=0;i<4;i++)
            gld16(srcA + (size_t)(32*i)*lda + k0, ldsA + w*1024 + i*4096);
        if (f16){
            #pragma unroll
            for (int i=0;i<4;i++)
                gld16(srcB16 + (size_t)(32*i)*ldb + k0, ldsB + w*1024 + i*4096);
        } else {
            #pragma unroll
            for (int s4=0;s4<4;s4++){
                int sl = chalf*4 + s4;
                const float* sp = srcBf + k0 + 8*(sl ^ (crow & 7));
                float4 f0 = *(const float4*)sp;
                float4 f1 = *(const float4*)(sp + 4);
                s16x8 pk;
                pk[0]=(short)f2bf(f0.x); pk[1]=(short)f2bf(f0.y);
                pk[2]=(short)f2bf(f0.z); pk[3]=(short)f2bf(f0.w);
                pk[4]=(short)f2bf(f1.x); pk[5]=(short)f2bf(f1.y);
                pk[6]=(short)f2bf(f1.z); pk[7]=(short)f2bf(f1.w);
                *(s16x8*)(ldsB + crow*128 + sl*16) = pk;
            }
        }
        __syncthreads();
        #pragma unroll
        for (int kk=0;kk<2;kk++){
            const int so = ((kk*4 + g) ^ (fr & 7)) * 16;
            s16x8 a[4], b[4];
            #pragma unroll
            for (int mt=0;mt<4;mt++)
                a[mt] = *(const s16x8*)(ldsA + (wm + mt*16 + fr)*128 + so);
            #pragma unroll
            for (int nt=0;nt<4;nt++)
                b[nt] = *(const s16x8*)(ldsB + (wn + nt*16 + fr)*128 + so);
            #pragma unroll
            for (int mt=0;mt<4;mt++)
                #pragma unroll
                for (int nt=0;nt<4;nt++)
                    acc[mt][nt] = __builtin_amdgcn_mfma_f32_16x16x32_bf16(
                                      a[mt], b[nt], acc[mt][nt], 0, 0, 0);
        }
        __syncthreads();
    }
    #pragma unroll
    for (int nt=0;nt<4;nt++){
        const int nc = n0 + wn + nt*16 + fr;
        #pragma unroll
        for (int mt=0;mt<4;mt++){
            #pragma unroll
            for (int r=0;r<4;r++){
                const int mr = m0 + wm + mt*16 + g*4 + r;
                const size_t idx = (size_t)mr * ldc + nc;
                if (f16) ((u16*)C)[idx] = f2bf(acc[mt][nt][r]);
                else     ((float*)C)[idx] = acc[mt][nt][r];
            }
        }
    }
}

// ---------------- MFMA flash attention (pipelined K/V staging) ----------------
__global__ __launch_bounds__(256) void attn_mfma(const u16* __restrict__ qkv,
                                                 const u16* __restrict__ vt,
                                                 u16* __restrict__ y){
    __shared__ __align__(16) char smem[33792];
    char* ldsK = smem;            // 2 x [64 j][32 d] bf16 (4KB each)
    char* ldsV = smem + 8192;     // 2 x [64 d][64 j] bf16 (8KB each)
    char* ldsP = smem + 24576;    // 4 x [16 q][72 j] bf16 (144B rows)

    const int qt = gridDim.x - 1 - blockIdx.x;     // long blocks first
    const int h = blockIdx.y, b = blockIdx.z;
    const int t = threadIdx.x, w = t >> 6, lane = t & 63;
    const int fr = lane & 15, g = lane >> 4;
    const int q0 = qt * 64;
    const int qw = q0 + w * 16;                    // wave's first q row
    const int bh = b * H_ + h;

    const int srow = t >> 2, sslot = t & 3;        // K: 64 rows x 4 slots
    const u16* srcK = qkv + (size_t)(b*T_ + srow)*2048 + 512 + h*32
                      + 8 * (sslot ^ swz(srow));
    const int vrow = t >> 3, vslot = t & 7;        // Vt: 2 halves of 32 rows x 8 slots
    const u16* srcV0 = vt + (size_t)(bh*64 + vrow)*T_      + 8 * (vslot ^ (vrow & 7));
    const u16* srcV1 = vt + (size_t)(bh*64 + 32 + vrow)*T_ + 8 * (vslot ^ (vrow & 7));

    s16x8 qf = *(const s16x8*)(qkv + (size_t)(b*T_ + qw + fr)*2048 + h*32 + g*8);

    char* pbase = ldsP + w * 2304;

    f32x4 o[4]; float m[4], l[4];
    #pragma unroll
    for (int f=0; f<4; f++) o[f] = (f32x4){0.f,0.f,0.f,0.f};
    #pragma unroll
    for (int r=0; r<4; r++){ m[r] = -3.0e38f; l[r] = 0.f; }

    const float scale = 0.17677669529663687f;      // 1/sqrt(32)
    const f32x4 zero = {0.f,0.f,0.f,0.f};

    // prologue stage -> buf 0
    gld16(srcK,      ldsK + w*1024);
    gld16(srcV0,     ldsV + w*1024);
    gld16(srcV1,     ldsV + 4096 + w*1024);

    const int ntt = qt + 1;
    for (int it = 0; it < ntt; ++it){
        const int cur = it & 1;
        if (it+1 < ntt){
            const int nb = cur^1;
            const int j1 = (it+1)*64;
            gld16(srcK + (size_t)j1*2048, ldsK + nb*4096 + w*1024);
            gld16(srcV0 + j1,             ldsV + nb*8192 + w*1024);
            gld16(srcV1 + j1,             ldsV + nb*8192 + 4096 + w*1024);
            vmwait<3>();
        } else {
            vmwait<0>();
        }
        SBAR();
        const int j0 = it*64;
        const char* bK = ldsK + cur*4096;
        const char* bV = ldsV + cur*8192;
        {
            f32x4 s[4];
            s16x8 kfr[4];
            #pragma unroll
            for (int f=0; f<4; f++){
                int row = f*16 + fr;
                kfr[f] = dsr(bK + row*64 + (g ^ swz(row))*16);
            }
            LGKM0(); SCHED0();
            #pragma unroll
            for (int f=0; f<4; f++)
                s[f] = __builtin_amdgcn_mfma_f32_16x16x32_bf16(qf, kfr[f], zero, 0,0,0);
            bool needmask = (j0 + 63 > qw);
            #pragma unroll
            for (int f=0; f<4; f++){
                int j = j0 + f*16 + fr;
                #pragma unroll
                for (int r=0; r<4; r++){
                    float sv = s[f][r] * scale;
                    if (needmask && j > qw + g*4 + r) sv = -3.0e38f;
                    s[f][r] = sv;
                }
            }
            float mx[4];
            #pragma unroll
            for (int r=0; r<4; r++)
                mx[r] = fmaxf(fmaxf(s[0][r], s[1][r]), fmaxf(s[2][r], s[3][r]));
            #pragma unroll
            for (int o2=8; o2>0; o2>>=1)
                #pragma unroll
                for (int r=0; r<4; r++) mx[r] = fmaxf(mx[r], __shfl_xor(mx[r], o2));
            float al[4];
            #pragma unroll
            for (int r=0; r<4; r++){
                float mn = fmaxf(m[r], mx[r]);
                al[r] = __expf(m[r] - mn);
                m[r] = mn;
            }
            float ps[4] = {0.f,0.f,0.f,0.f};
            #pragma unroll
            for (int f=0; f<4; f++)
                #pragma unroll
                for (int r=0; r<4; r++){
                    float p = __expf(s[f][r] - m[r]);
                    ps[r] += p;
                    *(u16*)(pbase + (g*4+r)*144 + (fr + 16*f)*2) = f2bf(p);
                }
            #pragma unroll
            for (int o2=8; o2>0; o2>>=1)
                #pragma unroll
                for (int r=0; r<4; r++) ps[r] += __shfl_xor(ps[r], o2);
            #pragma unroll
            for (int r=0; r<4; r++) l[r] = l[r]*al[r] + ps[r];
            #pragma unroll
            for (int f=0; f<4; f++)
                #pragma unroll
                for (int r=0; r<4; r++) o[f][r] *= al[r];
            #pragma unroll
            for (int kk=0; kk<2; kk++){
                s16x8 pa = *(const s16x8*)(pbase + fr*144 + kk*64 + g*16);
                s16x8 vbr[4];
                #pragma unroll
                for (int f=0; f<4; f++){
                    int row = f*16 + fr;
                    vbr[f] = dsr(bV + row*128 + (((kk*4+g) ^ (row&7))*16));
                }
                LGKM0(); SCHED0();
                #pragma unroll
                for (int f=0; f<4; f++)
                    o[f] = __builtin_amdgcn_mfma_f32_16x16x32_bf16(pa, vbr[f], o[f], 0,0,0);
            }
        }
        SBAR();
    }
    #pragma unroll
    for (int r=0; r<4; r++){
        float inv = 1.f / l[r];
        u16* yr = y + (size_t)(b*T_ + qw + g*4 + r)*1024 + h*64;
        #pragma unroll
        for (int f=0; f<4; f++)
            yr[fr + 16*f] = f2bf(o[f][r] * inv);
    }
}

// ------------------------------------------------------------------------------
extern "C" void kernel_launch(void* const* d_in, const int* in_sizes, int n_in,
                              void* d_out, int out_size, void* d_ws, size_t ws_size,
                              hipStream_t stream){
    const int*  ids   = (const int*) d_in[0];
    const void* te    = d_in[1];
    const void* pe    = d_in[2];
    const void* ln1_g = d_in[3];
    const void* ln1_b = d_in[4];
    const void* qp_w  = d_in[5];
    const void* qp_b  = d_in[6];
    const void* kp_w  = d_in[7];
    const void* kp_b  = d_in[8];
    const void* vp_w  = d_in[9];
    const void* vp_b  = d_in[10];
    const void* out_w = d_in[11];
    const void* out_b = d_in[12];
    const void* ln2_g = d_in[13];
    const void* ln2_b = d_in[14];
    const void* exp_w = d_in[15];
    const void* exp_b = d_in[16];
    const void* gate_w= d_in[17];
    const void* gate_b= d_in[18];
    const void* gup_w = d_in[19];
    const void* gup_b = d_in[20];
    const void* comp_w= d_in[21];
    const void* comp_b= d_in[22];
    const void* lnf_g = d_in[23];
    const void* lnf_b = d_in[24];

    char* ws = (char*)d_ws;
    int*   flag  = (int*)ws;
    float* bcat1 = (float*)(ws + 4096);                  // 2048 f32
    float* bcat2 = (float*)(ws + 4096 + 8192);           // 5120 f32
    float* x     = (float*)(ws + (1u<<20));              // [2048][1024] f32, 8MB
    u16*   hb    = (u16*)  (ws + (9u<<20));              // [2048][1024] bf16, 4MB
    u16*   qkvb  = (u16*)  (ws + (13u<<20));             // [2048][2048] bf16, 8MB (attn)
    u16*   yb    = (u16*)  (ws + (21u<<20));             // [2048][1024] bf16, 4MB (attn)
    u16*   vtb   = (u16*)  (ws + (25u<<20));             // [32][64][1024] bf16, 4MB (attn)
    u16*   eg1   = (u16*)  (ws + (13u<<20));             // [2048][5120] bf16, 20MB (ffn)
    u16*   wb    = (u16*)  (ws + (33u<<20));             // 10MB transposed-weight scratch
    u16*   te16  = (u16*)  (ws + ((size_t)44<<20));      // 65.6MB bf16 te (optional)

    const size_t need = ((size_t)44<<20) + (size_t)V_*D_*2 + (1u<<20);
    const bool pre = (ws_size >= need);

    detect_dtype<<<1, 256, 0, stream>>>((const u16*)te, flag);
    if (pre)
        conv_te<<<(V_*D_)/2048, 256, 0, stream>>>(te, te16, flag);
    embed_kernel<<<(M_*D_)/256, 256, 0, stream>>>(ids, te, pe, x, flag);

    for (int l=0; l<L_; l++){
        size_t lD = (size_t)l*D_;
        wt_tr<<<dim3(8,16,2), 256, 0, stream>>>(
            qp_w, (size_t)l*D_*512, wb,
            kp_w, (size_t)l*D_*512, wb + (size_t)512*1024,
            nullptr, 0, nullptr, 1024, 512, flag);
        wt_tr<<<dim3(16,16,2), 256, 0, stream>>>(
            vp_w,  (size_t)l*D_*1024,  wb + (size_t)1024*1024,
            out_w, (size_t)l*1024*1024, wb + (size_t)2048*1024,
            nullptr, 0, nullptr, 1024, 1024, flag);
        bias_cat<<<28, 256, 0, stream>>>(qp_b, kp_b, vp_b, exp_b, gate_b,
            (size_t)l*512, (size_t)l*512, (size_t)l*1024,
            (size_t)l*DE_, (size_t)l*1024, bcat1, bcat2, flag);

        ln_kernel<<<M_, 256, 0, stream>>>(x, ln1_g, ln1_b, lD, hb, flag);
        gemm_pipe<0,false,true,64,1><<<dim3(32,16), 256, 0, stream>>>(
            hb, 1024, wb, 1024, bcat1, 0, qkvb, 2048, 2048, 1024, flag);
        v_transpose<<<dim3(32,2,32), 256, 0, stream>>>(qkvb, vtb);
        attn_mfma<<<dim3(T_/64, H_, B_), 256, 0, stream>>>(qkvb, vtb, yb);
        gemm_pipe<0,true,false,64,2><<<dim3(16,16,2), 256, 0, stream>>>(
            yb, 1024, wb + (size_t)2048*1024, 1024,
            out_b, (size_t)l*1024, x, 1024, 1024, 1024, flag);

        wt_tr<<<dim3(64,16,1), 256, 0, stream>>>(
            exp_w, (size_t)l*D_*DE_, wb,
            nullptr,0,nullptr, nullptr,0,nullptr, 1024, 4096, flag);
        wt_tr<<<dim3(16,16,1), 256, 0, stream>>>(
            gate_w, (size_t)l*D_*1024, wb + (size_t)4096*1024,
            nullptr,0,nullptr, nullptr,0,nullptr, 1024, 1024, flag);
        ln_kernel<<<M_, 256, 0, stream>>>(x, ln2_g, ln2_b, lD, hb, flag);
        gemm_pipe<4,false,true,128,1><<<dim3(40,16), 256, 0, stream>>>(
            hb, 1024, wb, 1024, bcat2, 0, eg1, 5120, 5120, 1024, flag);
        wt_tr<<<dim3(64,16,1), 256, 0, stream>>>(
            gup_w, (size_t)l*1024*DE_, wb,
            nullptr,0,nullptr, nullptr,0,nullptr, 1024, 4096, flag);
        gemm_pipe<2,false,false,128,1><<<dim3(32,16), 256, 0, stream>>>(
            eg1 + 4096, 5120, wb, 1024,
            gup_b, (size_t)l*DE_, eg1, 5120, 4096, 1024, flag);
        wt_tr<<<dim3(16,64,1), 256, 0, stream>>>(
            comp_w, (size_t)l*DE_*1024, wb,
            nullptr,0,nullptr, nullptr,0,nullptr, 4096, 1024, flag);
        gemm_pipe<0,true,false,64,2><<<dim3(16,16,2), 256, 0, stream>>>(
            eg1, 5120, wb, 4096, comp_b, (size_t)l*1024, x, 1024, 1024, 4096, flag);
    }

    ln_kernel<<<M_, 256, 0, stream>>>(x, lnf_g, lnf_b, 0, hb, flag);
    if (pre)
        gemm_pipe<5,false,false,128,1><<<dim3(V_/128, M_/128), 256, 0, stream>>>(
            hb, 1024, te16, 1024, nullptr, 0, d_out, V_, V_, 1024, flag);
    else
        gemm_head_f32<<<dim3(V_/128, M_/128), 256, 0, stream>>>(
            hb, 1024, te, 1024, d_out, V_, V_, 1024, flag);
}